// Round 8
// baseline (26079.163 us; speedup 1.0000x reference)
//
#include <hip/hip_runtime.h>
#include <math.h>

// NTM recurrence. GEMMs via 3-product 2-plane bf16-split MFMA (~2^-17 rel err per GEMM,
// fp32 state masters). T-loop inside ONE persistent kernel (512 blocks, 2/CU co-resident).
// Coherence (r4/r7 scheme): NO cache fences. Mutable cross-block data via relaxed agent-scope
// (sc1) accesses (8B loads, write-through stores); read-only weights normal-cached (L2-resident
// forever). r8: the sc1 path is LATENCY-bound (88 K-iters/step x ~1us) -> BK=64 halves iter
// counts (P2 32->16, P3 16->8, P5 16->8); P4 re-tiled 32x128 BK=64 (16->8 iters, h-traffic
// 20->10 MB/step); P4's out/ea tiles overlap P5 in one phase slot (critical path 88->48 iters).
// B=256 T=128 I=512 H=512 N=1024 M=512 O=512
#define B_ 256
#define T_ 128
#define I_ 512
#define H_ 512
#define N_ 1024
#define M_ 512
#define O_ 512
#define EPS_ 1e-8f
#define NB_ 512  // persistent grid: 512 blocks x 256 thr, 2 blocks/CU co-resident

typedef unsigned short u16;
typedef unsigned long long u64;
typedef __attribute__((ext_vector_type(8))) short v8s;   // 8 bf16 = 4 VGPRs
typedef __attribute__((ext_vector_type(4))) float v4f;   // MFMA acc

#define MFMA(a, b, c) __builtin_amdgcn_mfma_f32_16x16x32_bf16(a, b, c, 0, 0, 0)

// plane strides (elements)
#define PL_BIG 1310720  // BigT [2560][512]: rows 0-511 Whw_k, 512-1023 Whr_k, 1024-1535 Wo, 1536-2559 Wea
#define PL_WXT 262144   // WxT  [512][512]
#define PL_WRT 262144   // WrT  [512][512]
#define PL_MEM 524288   // mem  [1024][512] / memT [512][1024]
#define PL_W   262144   // wwT [1024][256] / wr [256][1024]
#define PL_H   131072   // h [256][512], r [256][512], eT/aT [512][256]
#define PL_KH  262144   // kh [512][512]

// ---------------- sc1 (agent-coherent) access helpers ----------------
template <typename T>
__device__ __forceinline__ T lda_(const T* p) {
    return __hip_atomic_load(const_cast<T*>(p), __ATOMIC_RELAXED, __HIP_MEMORY_SCOPE_AGENT);
}
template <typename T>
__device__ __forceinline__ void sta_(T* p, T v) {
    __hip_atomic_store(p, v, __ATOMIC_RELAXED, __HIP_MEMORY_SCOPE_AGENT);
}
__device__ __forceinline__ uint4 ld16_(const u16* p) {  // 16B as 2 x dwordx2 sc1
    const u64* q = (const u64*)p;
    u64 lo = __hip_atomic_load(const_cast<u64*>(q), __ATOMIC_RELAXED, __HIP_MEMORY_SCOPE_AGENT);
    u64 hi = __hip_atomic_load(const_cast<u64*>(q + 1), __ATOMIC_RELAXED, __HIP_MEMORY_SCOPE_AGENT);
    uint4 r;
    r.x = (unsigned)lo; r.y = (unsigned)(lo >> 32);
    r.z = (unsigned)hi; r.w = (unsigned)(hi >> 32);
    return r;
}
__device__ __forceinline__ void st64_(u16* p, u16 a, u16 b, u16 c, u16 d) {
    u64 v = (u64)a | ((u64)b << 16) | ((u64)c << 32) | ((u64)d << 48);
    __hip_atomic_store((u64*)p, v, __ATOMIC_RELAXED, __HIP_MEMORY_SCOPE_AGENT);
}

// ---------------- scalar helpers ----------------
__device__ __forceinline__ float sigm_(float x) { return 1.f / (1.f + expf(-x)); }
__device__ __forceinline__ float softplus_(float x) { return x > 20.f ? x : log1pf(expf(x)); }
__device__ __forceinline__ u16 f2bf(float f) {
    unsigned u = __float_as_uint(f);
    u += 0x7fffu + ((u >> 16) & 1u);
    return (u16)(u >> 16);
}
__device__ __forceinline__ float bf2f(u16 h) { return __uint_as_float((unsigned)h << 16); }
__device__ __forceinline__ void split2(float f, u16& h, u16& m) {
    h = f2bf(f);
    m = f2bf(f - bf2f(h));
}

__device__ __forceinline__ float wave_sum_(float v) {
#pragma unroll
    for (int o = 32; o > 0; o >>= 1) v += __shfl_down(v, o);
    return v;
}
__device__ __forceinline__ float wave_max_(float v) {
#pragma unroll
    for (int o = 32; o > 0; o >>= 1) v = fmaxf(v, __shfl_down(v, o));
    return v;
}
__device__ float block_sum_(float v, float* s) {
    int lane = threadIdx.x & 63, wid = threadIdx.x >> 6, nw = blockDim.x >> 6;
    v = wave_sum_(v);
    if (lane == 0) s[wid] = v;
    __syncthreads();
    float r = (threadIdx.x < nw) ? s[threadIdx.x] : 0.f;
    if (wid == 0) { r = wave_sum_(r); if (lane == 0) s[0] = r; }
    __syncthreads();
    float out = s[0];
    __syncthreads();
    return out;
}
__device__ float block_max_(float v, float* s) {
    int lane = threadIdx.x & 63, wid = threadIdx.x >> 6, nw = blockDim.x >> 6;
    v = wave_max_(v);
    if (lane == 0) s[wid] = v;
    __syncthreads();
    float r = (threadIdx.x < nw) ? s[threadIdx.x] : -3.4e38f;
    if (wid == 0) { r = wave_max_(r); if (lane == 0) s[0] = r; }
    __syncthreads();
    float out = s[0];
    __syncthreads();
    return out;
}

// ---------------- grid barrier: per-block slots + release flag, NO fences ----------------
__device__ __forceinline__ void gsync(unsigned* slots, unsigned* flag, unsigned epoch) {
    __syncthreads();
    if (threadIdx.x == 0)
        __hip_atomic_store(&slots[blockIdx.x * 16], epoch, __ATOMIC_RELAXED,
                           __HIP_MEMORY_SCOPE_AGENT);
    if (blockIdx.x == 0) {
        while (__hip_atomic_load(&slots[threadIdx.x * 16], __ATOMIC_RELAXED,
                                 __HIP_MEMORY_SCOPE_AGENT) < epoch)
            __builtin_amdgcn_s_sleep(1);
        while (__hip_atomic_load(&slots[(threadIdx.x + 256) * 16], __ATOMIC_RELAXED,
                                 __HIP_MEMORY_SCOPE_AGENT) < epoch)
            __builtin_amdgcn_s_sleep(1);
        __syncthreads();  // all 512 slots arrived
        if (threadIdx.x == 0)
            __hip_atomic_store(flag, epoch, __ATOMIC_RELAXED, __HIP_MEMORY_SCOPE_AGENT);
    } else if (threadIdx.x == 0) {
        while (__hip_atomic_load(flag, __ATOMIC_RELAXED, __HIP_MEMORY_SCOPE_AGENT) < epoch)
            __builtin_amdgcn_s_sleep(1);
    }
    __syncthreads();
}

// ---------------- epilogues (per 16x16 fragment: rows r0..r0+3 (A-rows), col c (B-row)) ----------------
struct EpiEA0 {  // prologue ea only (separate kernel launch -> plain stores OK): r=b, c=m
    const float* bea; u16* eT; u16* aT;
    __device__ void operator()(int r0, int c, v4f v) const {
#pragma unroll
        for (int r = 0; r < 4; r++) {
            float val = v[r] + bea[c];
            u16* dst;
            int b = r0 + r;
            if (c < M_) { val = sigm_(val); dst = eT + (size_t)c * B_ + b; }
            else        { val = tanhf(val); dst = aT + (size_t)(c - M_) * B_ + b; }
            u16 h, m; split2(val, h, m);
            dst[0] = h; dst[PL_H] = m;
        }
    }
};
struct EpiR {  // C[b][m] -> r planes (sc1)
    u16* rp;
    __device__ void operator()(int r0, int c, v4f v) const {
#pragma unroll
        for (int r = 0; r < 4; r++) {
            u16 h, m; split2(v[r], h, m);
            size_t idx = (size_t)(r0 + r) * M_ + c;
            sta_(rp + idx, h); sta_(rp + PL_H + idx, m);
        }
    }
};
struct EpiH {  // C[b][hdim] + xwx(in d_out layout, cached read) + bh -> tanh -> h (sc1)
    const float* xwxt; const float* bh; float* hf; u16* hp;
    __device__ void operator()(int r0, int c, v4f v) const {
#pragma unroll
        for (int r = 0; r < 4; r++) {
            int b = r0 + r;
            float val = tanhf(v[r] + xwxt[(size_t)b * (T_ * O_) + c] + bh[c]);
            size_t idx = (size_t)b * H_ + c;
            sta_(hf + idx, val);
            u16 h, m; split2(val, h, m);
            sta_(hp + idx, h); sta_(hp + PL_H + idx, m);
        }
    }
};
struct EpiFused {  // c<1024: keys; 1024..1535: out; 1536..: ea(next step)
    const float* bhw; const float* bhr; const float* bo; const float* bea;
    u16* khp; float* outt; u16* eT; u16* aT;
    __device__ void operator()(int r0, int c, v4f v) const {
        if (c < 1024) {
            int head = c >> 9, key = c & 511;
            const float* bb = head ? bhr : bhw;
#pragma unroll
            for (int r = 0; r < 4; r++) {
                float val = tanhf(v[r] + bb[key]);
                size_t idx = (size_t)(head * 256 + r0 + r) * M_ + key;
                u16 h, m; split2(val, h, m);
                sta_(khp + idx, h); sta_(khp + PL_KH + idx, m);
            }
        } else if (c < 1536) {
            int o = c - 1024;
#pragma unroll
            for (int r = 0; r < 4; r++)
                outt[(size_t)(r0 + r) * (T_ * O_) + o] = sigm_(v[r] + bo[o]);  // host-read only
        } else {
            int m = c - 1536;
#pragma unroll
            for (int r = 0; r < 4; r++) {
                float val = v[r] + bea[m];
                u16* dst;
                int b = r0 + r;
                if (m < M_) { val = sigm_(val); dst = eT + (size_t)m * B_ + b; }
                else        { val = tanhf(val); dst = aT + (size_t)(m - M_) * B_ + b; }
                u16 h, mm; split2(val, h, mm);
                sta_(dst, h); sta_(dst + PL_H, mm);
            }
        }
    }
};

// ---------------- persistent-kernel args ----------------
struct NtmArgs {
    const u16 *BigT, *WxT, *WrT;
    u16 *mem_pl, *memT_pl, *wwT_pl, *wr_pl, *h_pl, *r_pl, *eT_pl, *aT_pl, *kh_pl;
    float *memf, *wwf, *wrf, *hf, *logits, *ssqp;
    const float *w6w, *w6r, *bh, *bhw, *bhr, *bea, *bo;
    float* out;
    unsigned* slots;
    unsigned* flag;
};

// ---------------- device: 3-product MFMA GEMM tile 64x64, BK=64 (phases 2,3) ----------------
// AS/BS: operand via sc1 8B loads (mutable) vs normal cached (read-only weight).
template <bool AS, bool BS, class Epi>
__device__ __forceinline__ void dev_g64(char* smc, const u16* __restrict__ Ap, int lda, int apl,
                                        const u16* __restrict__ Bp, int ldb, int bpl,
                                        int K, int row0, int col0, const Epi& epi) {
    typedef u16 (*T72)[64][72];
    T72 As = (T72)smc;             // 18432 B
    T72 Bs = (T72)(smc + 18432);   // 18432 B
    const int tid = threadIdx.x, lane = tid & 63, w = tid >> 6;
    const int wy = w >> 1, wx = w & 1, q = lane >> 4, l15 = lane & 15;
    uint4 ra[4], rb[4];
    auto loadA = [&](int k0) {
#pragma unroll
        for (int j = 0; j < 4; j++) {
            int s = j * 256 + tid, p = s >> 9, rr = (s >> 3) & 63, kg = s & 7;
            const u16* ap = Ap + (size_t)p * apl + (size_t)(row0 + rr) * lda + k0 + kg * 8;
            ra[j] = AS ? ld16_(ap) : *(const uint4*)ap;
        }
    };
    auto loadB = [&](int k0) {
#pragma unroll
        for (int j = 0; j < 4; j++) {
            int s = j * 256 + tid, p = s >> 9, rr = (s >> 3) & 63, kg = s & 7;
            const u16* bp = Bp + (size_t)p * bpl + (size_t)(col0 + rr) * ldb + k0 + kg * 8;
            rb[j] = BS ? ld16_(bp) : *(const uint4*)bp;
        }
    };
    v4f acc[2][2] = {};
    loadA(0); loadB(0);
    for (int k0 = 0; k0 < K; k0 += 64) {
#pragma unroll
        for (int j = 0; j < 4; j++) {
            int s = j * 256 + tid, p = s >> 9, rr = (s >> 3) & 63, kg = s & 7;
            *(uint4*)&As[p][rr][kg * 8] = ra[j];
            *(uint4*)&Bs[p][rr][kg * 8] = rb[j];
        }
        __syncthreads();
        if (k0 + 64 < K) { loadA(k0 + 64); loadB(k0 + 64); }
        v8s af[2][2][2], bf[2][2][2];  // [mt|nt][plane][k-half]
#pragma unroll
        for (int mt = 0; mt < 2; mt++)
#pragma unroll
            for (int p = 0; p < 2; p++)
#pragma unroll
                for (int h = 0; h < 2; h++) {
                    af[mt][p][h] = *(const v8s*)&As[p][wy * 32 + mt * 16 + l15][h * 32 + q * 8];
                    bf[mt][p][h] = *(const v8s*)&Bs[p][wx * 32 + mt * 16 + l15][h * 32 + q * 8];
                }
#pragma unroll
        for (int mt = 0; mt < 2; mt++)
#pragma unroll
            for (int nt = 0; nt < 2; nt++) {
                v4f c = acc[mt][nt];
#pragma unroll
                for (int h = 0; h < 2; h++) {
                    c = MFMA(af[mt][0][h], bf[nt][0][h], c);
                    c = MFMA(af[mt][0][h], bf[nt][1][h], c);
                    c = MFMA(af[mt][1][h], bf[nt][0][h], c);
                }
                acc[mt][nt] = c;
            }
        __syncthreads();
    }
#pragma unroll
    for (int mt = 0; mt < 2; mt++)
#pragma unroll
        for (int nt = 0; nt < 2; nt++)
            epi(row0 + wy * 32 + mt * 16 + q * 4, col0 + wx * 32 + nt * 16 + l15, acc[mt][nt]);
}

// ---------------- device: 3-product MFMA GEMM tile 32x128, BK=64 (phase 4; B cached) ----------------
template <class Epi>
__device__ __forceinline__ void dev_g32x128(char* smc, const u16* __restrict__ Ap, int lda, int apl,
                                            const u16* __restrict__ Bp, int ldb, int bpl,
                                            int K, int row0, int col0, const Epi& epi) {
    typedef u16 (*TA)[32][72];
    typedef u16 (*TB)[128][72];
    TA As = (TA)smc;              // 9216 B
    TB Bs = (TB)(smc + 9216);     // 36864 B
    const int tid = threadIdx.x, lane = tid & 63, w = tid >> 6;
    const int wy = w >> 1, wx = w & 1, q = lane >> 4, l15 = lane & 15;
    uint4 ra[2], rb[8];
    auto loadA = [&](int k0) {
#pragma unroll
        for (int j = 0; j < 2; j++) {
            int s = j * 256 + tid, p = s >> 8, rr = (s >> 3) & 31, kg = s & 7;
            ra[j] = ld16_(Ap + (size_t)p * apl + (size_t)(row0 + rr) * lda + k0 + kg * 8);
        }
    };
    auto loadB = [&](int k0) {
#pragma unroll
        for (int j = 0; j < 8; j++) {
            int s = j * 256 + tid, p = s >> 10, rr = (s >> 3) & 127, kg = s & 7;
            rb[j] = *(const uint4*)(Bp + (size_t)p * bpl + (size_t)(col0 + rr) * ldb + k0 + kg * 8);
        }
    };
    v4f acc[4] = {};
    loadA(0); loadB(0);
    for (int k0 = 0; k0 < K; k0 += 64) {
#pragma unroll
        for (int j = 0; j < 2; j++) {
            int s = j * 256 + tid, p = s >> 8, rr = (s >> 3) & 31, kg = s & 7;
            *(uint4*)&As[p][rr][kg * 8] = ra[j];
        }
#pragma unroll
        for (int j = 0; j < 8; j++) {
            int s = j * 256 + tid, p = s >> 10, rr = (s >> 3) & 127, kg = s & 7;
            *(uint4*)&Bs[p][rr][kg * 8] = rb[j];
        }
        __syncthreads();
        if (k0 + 64 < K) { loadA(k0 + 64); loadB(k0 + 64); }
        v8s af[2][2];  // [plane][k-half]
#pragma unroll
        for (int p = 0; p < 2; p++)
#pragma unroll
            for (int h = 0; h < 2; h++)
                af[p][h] = *(const v8s*)&As[p][wy * 16 + l15][h * 32 + q * 8];
        v8s bf[4][2][2];
#pragma unroll
        for (int nt = 0; nt < 4; nt++)
#pragma unroll
            for (int p = 0; p < 2; p++)
#pragma unroll
                for (int h = 0; h < 2; h++)
                    bf[nt][p][h] = *(const v8s*)&Bs[p][wx * 64 + nt * 16 + l15][h * 32 + q * 8];
#pragma unroll
        for (int nt = 0; nt < 4; nt++) {
            v4f c = acc[nt];
#pragma unroll
            for (int h = 0; h < 2; h++) {
                c = MFMA(af[0][h], bf[nt][0][h], c);
                c = MFMA(af[0][h], bf[nt][1][h], c);
                c = MFMA(af[1][h], bf[nt][0][h], c);
            }
            acc[nt] = c;
        }
        __syncthreads();
    }
#pragma unroll
    for (int nt = 0; nt < 4; nt++)
        epi(row0 + wy * 16 + q * 4, col0 + wx * 64 + nt * 16 + l15, acc[nt]);
}

// ---------------- device: memupd (BK=32, known-good; Se/Sa + mem update + row ssq) ----------------
__device__ void dev_memupd(char* smc, int bid, const NtmArgs& A) {
    typedef u16 (*T64)[64][40];
    T64 As = (T64)smc;                 // 10240 B
    T64 Be = (T64)(smc + 10240);
    T64 Ba = (T64)(smc + 20480);
    float* ssqs = (float*)(smc + 30720);
    const int tid = threadIdx.x, lane = tid & 63, w = tid >> 6;
    const int wy = w >> 1, wx = w & 1, q = lane >> 4, l15 = lane & 15;
    const int bx = bid & 7, by = bid >> 3;
    const int row0 = by * 64, col0 = bx * 64;  // row=n, col=m
    if (tid < 64) ssqs[tid] = 0.f;
    uint4 rA[2], rE[2], rB[2];
    auto loadAll = [&](int k0) {
#pragma unroll
        for (int j = 0; j < 2; j++) {
            int s = j * 256 + tid, p = s >> 8, rr = (s >> 2) & 63, kg = s & 3;
            rA[j] = ld16_(A.wwT_pl + (size_t)p * PL_W + (size_t)(row0 + rr) * B_ + k0 + kg * 8);
            rE[j] = ld16_(A.eT_pl + (size_t)p * PL_H + (size_t)(col0 + rr) * B_ + k0 + kg * 8);
            rB[j] = ld16_(A.aT_pl + (size_t)p * PL_H + (size_t)(col0 + rr) * B_ + k0 + kg * 8);
        }
    };
    v4f ae[2][2] = {}, aa[2][2] = {};
    loadAll(0);
    for (int k0 = 0; k0 < B_; k0 += 32) {
#pragma unroll
        for (int j = 0; j < 2; j++) {
            int s = j * 256 + tid, p = s >> 8, rr = (s >> 2) & 63, kg = s & 3;
            *(uint4*)&As[p][rr][kg * 8] = rA[j];
            *(uint4*)&Be[p][rr][kg * 8] = rE[j];
            *(uint4*)&Ba[p][rr][kg * 8] = rB[j];
        }
        __syncthreads();
        if (k0 + 32 < B_) loadAll(k0 + 32);
        v8s af[2][2], be[2][2], ba[2][2];
#pragma unroll
        for (int mt = 0; mt < 2; mt++) {
            af[mt][0] = *(const v8s*)&As[0][wy * 32 + mt * 16 + l15][q * 8];
            af[mt][1] = *(const v8s*)&As[1][wy * 32 + mt * 16 + l15][q * 8];
            be[mt][0] = *(const v8s*)&Be[0][wx * 32 + mt * 16 + l15][q * 8];
            be[mt][1] = *(const v8s*)&Be[1][wx * 32 + mt * 16 + l15][q * 8];
            ba[mt][0] = *(const v8s*)&Ba[0][wx * 32 + mt * 16 + l15][q * 8];
            ba[mt][1] = *(const v8s*)&Ba[1][wx * 32 + mt * 16 + l15][q * 8];
        }
#pragma unroll
        for (int mt = 0; mt < 2; mt++)
#pragma unroll
            for (int nt = 0; nt < 2; nt++) {
                v4f c = ae[mt][nt];
                c = MFMA(af[mt][0], be[nt][0], c);
                c = MFMA(af[mt][0], be[nt][1], c);
                c = MFMA(af[mt][1], be[nt][0], c);
                ae[mt][nt] = c;
                v4f d = aa[mt][nt];
                d = MFMA(af[mt][0], ba[nt][0], d);
                d = MFMA(af[mt][0], ba[nt][1], d);
                d = MFMA(af[mt][1], ba[nt][0], d);
                aa[mt][nt] = d;
            }
        __syncthreads();
    }
    const float invB = 1.f / (float)B_;
#pragma unroll
    for (int mt = 0; mt < 2; mt++)
#pragma unroll
        for (int nt = 0; nt < 2; nt++) {
            int r0 = row0 + wy * 32 + mt * 16 + q * 4;
            int c  = col0 + wx * 32 + nt * 16 + l15;
            u16 hv[4][2];
#pragma unroll
            for (int r = 0; r < 4; r++) {
                size_t idx = (size_t)(r0 + r) * M_ + c;
                float old = A.memf[idx];  // block-private tile (same block every step): cached
                float nv = old * (1.f - ae[mt][nt][r] * invB) + aa[mt][nt][r] * invB;
                A.memf[idx] = nv;
                u16 h, m; split2(nv, h, m);
                sta_(A.mem_pl + idx, h); sta_(A.mem_pl + PL_MEM + idx, m);
                hv[r][0] = h; hv[r][1] = m;
                atomicAdd(&ssqs[r0 + r - row0], nv * nv);
            }
            size_t tb = (size_t)c * N_ + r0;
            st64_(A.memT_pl + tb, hv[0][0], hv[1][0], hv[2][0], hv[3][0]);
            st64_(A.memT_pl + PL_MEM + tb, hv[0][1], hv[1][1], hv[2][1], hv[3][1]);
        }
    __syncthreads();
    if (tid < 64) sta_(A.ssqp + (size_t)(row0 + tid) * 8 + bx, ssqs[tid]);
}

// ---------------- device: logits = (kh @ mem^T) * invn  (64x64, BK=64) ----------------
__device__ void dev_logits(char* smc, int bx, int by, const NtmArgs& A) {
    typedef u16 (*T72)[64][72];
    T72 As = (T72)smc;
    T72 Bs = (T72)(smc + 18432);
    float* invn_s = (float*)(smc + 36864);
    const int tid = threadIdx.x, lane = tid & 63, w = tid >> 6;
    const int wy = w >> 1, wx = w & 1, q = lane >> 4, l15 = lane & 15;
    const int row0 = by * 64, col0 = bx * 64;  // row in [0,512), col=n
    if (tid < 64) {
        float s = 0.f;
#pragma unroll
        for (int j = 0; j < 8; j++) s += lda_(A.ssqp + (size_t)(col0 + tid) * 8 + j);
        invn_s[tid] = 1.f / (sqrtf(s) + EPS_);
    }
    uint4 ra[4], rb[4];
    auto loadAll = [&](int k0) {
#pragma unroll
        for (int j = 0; j < 4; j++) {
            int s = j * 256 + tid, p = s >> 9, rr = (s >> 3) & 63, kg = s & 7;
            ra[j] = ld16_(A.kh_pl + (size_t)p * PL_KH + (size_t)(row0 + rr) * M_ + k0 + kg * 8);
            rb[j] = ld16_(A.mem_pl + (size_t)p * PL_MEM + (size_t)(col0 + rr) * M_ + k0 + kg * 8);
        }
    };
    v4f acc[2][2] = {};
    loadAll(0);
    for (int k0 = 0; k0 < M_; k0 += 64) {
#pragma unroll
        for (int j = 0; j < 4; j++) {
            int s = j * 256 + tid, p = s >> 9, rr = (s >> 3) & 63, kg = s & 7;
            *(uint4*)&As[p][rr][kg * 8] = ra[j];
            *(uint4*)&Bs[p][rr][kg * 8] = rb[j];
        }
        __syncthreads();
        if (k0 + 64 < M_) loadAll(k0 + 64);
        v8s af[2][2][2], bf[2][2][2];
#pragma unroll
        for (int mt = 0; mt < 2; mt++)
#pragma unroll
            for (int p = 0; p < 2; p++)
#pragma unroll
                for (int h = 0; h < 2; h++) {
                    af[mt][p][h] = *(const v8s*)&As[p][wy * 32 + mt * 16 + l15][h * 32 + q * 8];
                    bf[mt][p][h] = *(const v8s*)&Bs[p][wx * 32 + mt * 16 + l15][h * 32 + q * 8];
                }
#pragma unroll
        for (int mt = 0; mt < 2; mt++)
#pragma unroll
            for (int nt = 0; nt < 2; nt++) {
                v4f c = acc[mt][nt];
#pragma unroll
                for (int h = 0; h < 2; h++) {
                    c = MFMA(af[mt][0][h], bf[nt][0][h], c);
                    c = MFMA(af[mt][0][h], bf[nt][1][h], c);
                    c = MFMA(af[mt][1][h], bf[nt][0][h], c);
                }
                acc[mt][nt] = c;
            }
        __syncthreads();
    }
#pragma unroll
    for (int mt = 0; mt < 2; mt++)
#pragma unroll
        for (int nt = 0; nt < 2; nt++) {
            int r0 = row0 + wy * 32 + mt * 16 + q * 4;
            int c  = col0 + wx * 32 + nt * 16 + l15;
            float in_ = invn_s[c - col0];
#pragma unroll
            for (int r = 0; r < 4; r++)
                sta_(A.logits + (size_t)(r0 + r) * N_ + c, acc[mt][nt][r] * in_);
        }
}

// ---------------- device: addressing tail ----------------
__device__ void dev_addr(char* smc, int row, const NtmArgs& A) {
    float* wgs = (float*)smc;           // N_ floats = 4096 B
    float* red = (float*)(smc + 4096);  // 8 floats
    int head = row >> 8, b = row & 255;
    const float* w6 = head ? A.w6r : A.w6w;
    const float* bias = head ? A.bhr : A.bhw;
    float* wf = head ? A.wrf : A.wwf;   // master row b: exclusively owned by this block
    int tid = threadIdx.x;
    float d0 = 0, d1 = 0, d2 = 0, d3 = 0, d4 = 0, d5 = 0, ssq = 0;
#pragma unroll
    for (int j = 0; j < 2; j++) {
        int k = tid + j * 256;
        float hv = lda_(A.hf + (size_t)b * H_ + k);
        const float* wk = w6 + k * 6;
        d0 += hv * wk[0]; d1 += hv * wk[1]; d2 += hv * wk[2];
        d3 += hv * wk[3]; d4 += hv * wk[4]; d5 += hv * wk[5];
        size_t ki = (size_t)row * M_ + k;
        float kv = bf2f(lda_(A.kh_pl + ki)) + bf2f(lda_(A.kh_pl + PL_KH + ki));
        ssq += kv * kv;
    }
    d0 = block_sum_(d0, red); d1 = block_sum_(d1, red); d2 = block_sum_(d2, red);
    d3 = block_sum_(d3, red); d4 = block_sum_(d4, red); d5 = block_sum_(d5, red);
    ssq = block_sum_(ssq, red);
    float beta = softplus_(d0 + bias[M_]);
    float g = sigm_(d1 + bias[M_ + 1]);
    float a0 = d2 + bias[M_ + 2], a1 = d3 + bias[M_ + 3], a2 = d4 + bias[M_ + 4];
    float mx3 = fmaxf(a0, fmaxf(a1, a2));
    float e0 = expf(a0 - mx3), e1 = expf(a1 - mx3), e2 = expf(a2 - mx3);
    float es = e0 + e1 + e2;
    float s0 = e0 / es, s1 = e1 / es, s2 = e2 / es;
    float gamma = 1.f + softplus_(d5 + bias[M_ + 5]);
    float rowsc = beta / (sqrtf(ssq) + EPS_);
    const u64* lp = (const u64*)(A.logits + (size_t)row * N_ + tid * 4);
    u64 la = lda_(lp), lb = lda_(lp + 1);
    float l[4];
    l[0] = __uint_as_float((unsigned)la) * rowsc;
    l[1] = __uint_as_float((unsigned)(la >> 32)) * rowsc;
    l[2] = __uint_as_float((unsigned)lb) * rowsc;
    l[3] = __uint_as_float((unsigned)(lb >> 32)) * rowsc;
    float mx = fmaxf(fmaxf(l[0], l[1]), fmaxf(l[2], l[3]));
    mx = block_max_(mx, red);
    float ex[4], sum = 0.f;
#pragma unroll
    for (int j = 0; j < 4; j++) { ex[j] = expf(l[j] - mx); sum += ex[j]; }
    sum = block_sum_(sum, red);
    float inv = 1.f / sum;
    float wprev[4];
#pragma unroll
    for (int j = 0; j < 4; j++) wprev[j] = wf[(size_t)b * N_ + tid * 4 + j];
#pragma unroll
    for (int j = 0; j < 4; j++) wgs[tid * 4 + j] = g * ex[j] * inv + (1.f - g) * wprev[j];
    __syncthreads();
    float wp[4], psum = 0.f;
#pragma unroll
    for (int j = 0; j < 4; j++) {
        int n = tid * 4 + j;
        float wt = s0 * wgs[(n + 1) & (N_ - 1)] + s1 * wgs[n] + s2 * wgs[(n - 1) & (N_ - 1)];
        float v = expf(gamma * logf(wt));
        wp[j] = v; psum += v;
    }
    psum = block_sum_(psum, red);
    float invp = 1.f / (psum + EPS_);
#pragma unroll
    for (int j = 0; j < 4; j++) {
        int n = tid * 4 + j;
        float val = wp[j] * invp;
        wf[(size_t)b * N_ + n] = val;  // block-private master: cached
        u16 h, m; split2(val, h, m);
        if (head == 0) {
            size_t tb = (size_t)n * B_ + b;
            sta_(A.wwT_pl + tb, h); sta_(A.wwT_pl + PL_W + tb, m);
        } else {
            size_t idx = (size_t)b * N_ + n;
            sta_(A.wr_pl + idx, h); sta_(A.wr_pl + PL_W + idx, m);
        }
    }
}

// ---------------- persistent kernel: the whole T-loop ----------------
__global__ __launch_bounds__(256, 2) void ntm_loop(NtmArgs A) {
    __shared__ __align__(16) char sm[47104];
    const int bid = blockIdx.x;
    unsigned ep = 0;
    for (int t = 0; t < T_; t++) {
        // 1. mem update + row-ssq partials  [n x m, K=256]  (128 tiles 64x64, BK=32)
        if (bid < 128) dev_memupd(sm, bid, A);
        gsync(A.slots, A.flag, ++ep);
        // 2. r = wr @ mem  [256 x 512, K=1024]  (32 tiles 64x64, BK=64 -> 16 iters)
        if (bid < 32) {
            int bx = bid & 7, by = bid >> 3;
            dev_g64<true, true>(sm, A.wr_pl, 1024, PL_W, A.memT_pl, 1024, PL_MEM, 1024,
                                by * 64, bx * 64, EpiR{A.r_pl});
        }
        gsync(A.slots, A.flag, ++ep);
        // 3. h = tanh(xwx + r @ Wr + bh)  [256 x 512, K=512]  (32 tiles 64x64, BK=64 -> 8 iters)
        if (bid < 32) {
            int bx = bid & 7, by = bid >> 3;
            dev_g64<true, false>(sm, A.r_pl, 512, PL_H, A.WrT, 512, PL_WRT, 512,
                                 by * 64, bx * 64,
                                 EpiH{A.out + (size_t)t * O_, A.bh, A.hf, A.h_pl});
        }
        gsync(A.slots, A.flag, ++ep);
        // 4a. kh = tanh(h @ [Whw_k|Whr_k])  (64 tiles 32x128: bx=bid&7 -> same BigT slice per XCD)
        if (bid < 64) {
            int bx = bid & 7, by = bid >> 3;
            dev_g32x128(sm, A.h_pl, 512, PL_H, A.BigT, 512, PL_BIG, 512,
                        by * 32, bx * 128,
                        EpiFused{A.bhw, A.bhr, A.bo, A.bea, A.kh_pl,
                                 A.out + (size_t)t * O_, A.eT_pl, A.aT_pl});
        }
        gsync(A.slots, A.flag, ++ep);
        // 4b+5 overlapped: blocks 0..127 logits (needs kh); blocks 128..223 out/ea tiles
        if (bid < 128) {
            int g = bid & 7, idx = bid >> 3;           // idx 0..15
            int bx = g * 2 + (idx & 1), by = idx >> 1; // bx 0..15, by 0..7
            dev_logits(sm, bx, by, A);
        } else if (bid < 224) {
            int b2 = bid - 128;                        // 0..95
            int bx = 8 + b2 % 12, by = b2 / 12;        // bx 8..19, by 0..7
            dev_g32x128(sm, A.h_pl, 512, PL_H, A.BigT, 512, PL_BIG, 512,
                        by * 32, bx * 128,
                        EpiFused{A.bhw, A.bhr, A.bo, A.bea, A.kh_pl,
                                 A.out + (size_t)t * O_, A.eT_pl, A.aT_pl});
        }
        gsync(A.slots, A.flag, ++ep);
        // 6. addressing tail -> ww/wr masters + planes  (512 rows, 1 per block)
        for (int row = bid; row < 2 * B_; row += NB_) dev_addr(sm, row, A);
        gsync(A.slots, A.flag, ++ep);
    }
}

// ---------------- generic 3-product MFMA GEMM (prologue use only) ----------------
template <int TM, class Epi>
__global__ __launch_bounds__(256) void gemm2(const u16* __restrict__ Ap, int lda, int apl,
                                             const u16* __restrict__ Bp, int ldb, int bpl,
                                             int K, Epi epi) {
    constexpr int AL = (TM * 32 * 2) / (256 * 8);
    constexpr int MT = TM / 32;
    __shared__ u16 As[2][TM][40];
    __shared__ u16 Bs[2][64][40];
    const int tid = threadIdx.x, lane = tid & 63, w = tid >> 6;
    const int wy = w >> 1, wx = w & 1, q = lane >> 4, l15 = lane & 15;
    const int row0 = blockIdx.y * TM, col0 = blockIdx.x * 64;
    uint4 ra[AL], rb[2];
    auto loadA = [&](int k0) {
#pragma unroll
        for (int j = 0; j < AL; j++) {
            int s = j * 256 + tid, p = s / (TM * 4), rr = (s >> 2) % TM, kg = s & 3;
            ra[j] = *(const uint4*)(Ap + (size_t)p * apl + (size_t)(row0 + rr) * lda + k0 + kg * 8);
        }
    };
    auto loadB = [&](int k0) {
#pragma unroll
        for (int j = 0; j < 2; j++) {
            int s = j * 256 + tid, p = s >> 8, rr = (s >> 2) & 63, kg = s & 3;
            rb[j] = *(const uint4*)(Bp + (size_t)p * bpl + (size_t)(col0 + rr) * ldb + k0 + kg * 8);
        }
    };
    v4f acc[MT][2] = {};
    loadA(0); loadB(0);
    for (int k0 = 0; k0 < K; k0 += 32) {
#pragma unroll
        for (int j = 0; j < AL; j++) {
            int s = j * 256 + tid, p = s / (TM * 4), rr = (s >> 2) % TM, kg = s & 3;
            *(uint4*)&As[p][rr][kg * 8] = ra[j];
        }
#pragma unroll
        for (int j = 0; j < 2; j++) {
            int s = j * 256 + tid, p = s >> 8, rr = (s >> 2) & 63, kg = s & 3;
            *(uint4*)&Bs[p][rr][kg * 8] = rb[j];
        }
        __syncthreads();
        if (k0 + 32 < K) { loadA(k0 + 32); loadB(k0 + 32); }
        v8s af[MT][2], bf[2][2];
#pragma unroll
        for (int mt = 0; mt < MT; mt++) {
            af[mt][0] = *(const v8s*)&As[0][wy * (TM / 2) + mt * 16 + l15][q * 8];
            af[mt][1] = *(const v8s*)&As[1][wy * (TM / 2) + mt * 16 + l15][q * 8];
        }
#pragma unroll
        for (int nt = 0; nt < 2; nt++) {
            bf[nt][0] = *(const v8s*)&Bs[0][wx * 32 + nt * 16 + l15][q * 8];
            bf[nt][1] = *(const v8s*)&Bs[1][wx * 32 + nt * 16 + l15][q * 8];
        }
#pragma unroll
        for (int mt = 0; mt < MT; mt++)
#pragma unroll
            for (int nt = 0; nt < 2; nt++) {
                v4f c = acc[mt][nt];
                c = MFMA(af[mt][0], bf[nt][0], c);
                c = MFMA(af[mt][0], bf[nt][1], c);
                c = MFMA(af[mt][1], bf[nt][0], c);
                acc[mt][nt] = c;
            }
        __syncthreads();
    }
#pragma unroll
    for (int mt = 0; mt < MT; mt++)
#pragma unroll
        for (int nt = 0; nt < 2; nt++)
            epi(row0 + wy * (TM / 2) + mt * 16 + q * 4, col0 + wx * 32 + nt * 16 + l15, acc[mt][nt]);
}

// ---------------- xwx GEMM: rows (t*256+b), A split from f32 on the fly, out -> d_out[b][t][:] ----------------
__global__ __launch_bounds__(256) void gemm2_xwx(const float* __restrict__ x, const u16* __restrict__ WxT,
                                                 float* __restrict__ outbuf) {
    __shared__ u16 As[2][64][40];
    __shared__ u16 Bs[2][64][40];
    const int tid = threadIdx.x, lane = tid & 63, w = tid >> 6;
    const int wy = w >> 1, wx = w & 1, q = lane >> 4, l15 = lane & 15;
    const int row0 = blockIdx.y * 64, col0 = blockIdx.x * 64;
    const int sr = tid >> 2, ss = (tid & 3) * 8;
    const int arow = row0 + sr, ab = arow & 255, at = arow >> 8;
    const float* Asrc = x + ((size_t)ab * T_ + at) * I_ + ss;
    v4f acc[2][2] = {};
    for (int k0 = 0; k0 < I_; k0 += 32) {
        float4 f0 = *(const float4*)(Asrc + k0);
        float4 f1 = *(const float4*)(Asrc + k0 + 4);
        float av8[8] = {f0.x, f0.y, f0.z, f0.w, f1.x, f1.y, f1.z, f1.w};
#pragma unroll
        for (int j = 0; j < 8; j++) {
            u16 h, m; split2(av8[j], h, m);
            As[0][sr][ss + j] = h; As[1][sr][ss + j] = m;
        }
#pragma unroll
        for (int p = 0; p < 2; p++)
            *(uint4*)&Bs[p][sr][ss] = *(const uint4*)&WxT[(size_t)p * PL_WXT + (size_t)(col0 + sr) * I_ + k0 + ss];
        __syncthreads();
        v8s af[2][2], bf[2][2];
#pragma unroll
        for (int mt = 0; mt < 2; mt++) {
            af[mt][0] = *(const v8s*)&As[0][wy * 32 + mt * 16 + l15][q * 8];
            af[mt][1] = *(const v8s*)&As[1][wy * 32 + mt * 16 + l15][q * 8];
            bf[mt][0] = *(const v8s*)&Bs[0][wx * 32 + mt * 16 + l15][q * 8];
            bf[mt][1] = *(const v8s*)&Bs[1][wx * 32 + mt * 16 + l15][q * 8];
        }
#pragma unroll
        for (int mt = 0; mt < 2; mt++)
#pragma unroll
            for (int nt = 0; nt < 2; nt++) {
                v4f c = acc[mt][nt];
                c = MFMA(af[mt][0], bf[nt][0], c);
                c = MFMA(af[mt][0], bf[nt][1], c);
                c = MFMA(af[mt][1], bf[nt][0], c);
                acc[mt][nt] = c;
            }
        __syncthreads();
    }
#pragma unroll
    for (int mt = 0; mt < 2; mt++)
#pragma unroll
        for (int nt = 0; nt < 2; nt++) {
            int r0 = row0 + wy * 32 + mt * 16 + q * 4;
            int c  = col0 + wx * 32 + nt * 16 + l15;
#pragma unroll
            for (int r = 0; r < 4; r++) {
                int row = r0 + r, b = row & 255, t = row >> 8;
                outbuf[((size_t)b * T_ + t) * O_ + c] = acc[mt][nt][r];
            }
        }
}

// ---------------- decomp: transpose + split2: in f32 [R][ldin] cols c0.. -> planes [C][R] ----------------
__global__ __launch_bounds__(256) void decomp_t(const float* __restrict__ in, int ldin, int c0,
                                                int R, u16* __restrict__ outp, int opl) {
    __shared__ float Ls[32][33];
    const int r0 = blockIdx.x * 32, cB = blockIdx.y * 32;
    const int tid = threadIdx.x;
    int lr = tid >> 3, lc = (tid & 7) * 4;
#pragma unroll
    for (int j = 0; j < 4; j++)
        Ls[lr][lc + j] = in[(size_t)(r0 + lr) * ldin + c0 + cB + lc + j];
    __syncthreads();
    int lc2 = tid >> 3, lr2 = (tid & 7) * 4;
    u16 hv[4], mv[4];
#pragma unroll
    for (int j = 0; j < 4; j++) split2(Ls[lr2 + j][lc2], hv[j], mv[j]);
    size_t base = (size_t)(cB + lc2) * R + r0 + lr2;
    *(ushort4*)&outp[0 * (size_t)opl + base] = make_ushort4(hv[0], hv[1], hv[2], hv[3]);
    *(ushort4*)&outp[1 * (size_t)opl + base] = make_ushort4(mv[0], mv[1], mv[2], mv[3]);
}

// ---------------- init / misc ----------------
__global__ __launch_bounds__(512) void wh6_kernel(const float* __restrict__ Whw, const float* __restrict__ Whr,
                                                  float* __restrict__ w6w, float* __restrict__ w6r,
                                                  unsigned* __restrict__ barz) {
    int k = threadIdx.x;
    if (blockIdx.x == 0) {
        for (int i = k; i < NB_ * 16 + 16; i += 512) barz[i] = 0u;  // 512 slots*16 + flag line
    }
    const float* src = blockIdx.x ? Whr : Whw;
    float* dst = blockIdx.x ? w6r : w6w;
#pragma unroll
    for (int j = 0; j < 6; j++) dst[k * 6 + j] = src[(size_t)k * (M_ + 6) + M_ + j];
}
__global__ __launch_bounds__(256) void init_mem(const float* __restrict__ mem0, float* __restrict__ memf,
                                                u16* __restrict__ mem_pl, u16* __restrict__ memT_pl) {
    int n = blockIdx.x;
    for (int c = threadIdx.x; c < M_; c += 256) {
        float v = mem0[(size_t)n * M_ + c];
        size_t idx = (size_t)n * M_ + c;
        memf[idx] = v;
        u16 h, m; split2(v, h, m);
        mem_pl[idx] = h; mem_pl[PL_MEM + idx] = m;
        size_t tb = (size_t)c * N_ + n;
        memT_pl[tb] = h; memT_pl[PL_MEM + tb] = m;
    }
}
__global__ __launch_bounds__(256) void init_w(const float* __restrict__ wr0, const float* __restrict__ ww0,
                                              float* __restrict__ wrf, float* __restrict__ wwf,
                                              u16* __restrict__ wr_pl, u16* __restrict__ wwT_pl) {
    int b = blockIdx.x;
    for (int n = threadIdx.x; n < N_; n += 256) {
        size_t idx = (size_t)b * N_ + n;
        float vw = ww0[idx]; wwf[idx] = vw;
        u16 h, m; split2(vw, h, m);
        size_t tb = (size_t)n * B_ + b;
        wwT_pl[tb] = h; wwT_pl[PL_W + tb] = m;
        float vr = wr0[idx]; wrf[idx] = vr;
        split2(vr, h, m);
        wr_pl[idx] = h; wr_pl[PL_W + idx] = m;
    }
}
__global__ __launch_bounds__(64) void init_h(const float* __restrict__ h0, float* __restrict__ hf,
                                             u16* __restrict__ hp) {
    int b = blockIdx.x;
    for (int c = threadIdx.x; c < H_; c += 64) {
        size_t idx = (size_t)b * H_ + c;
        float v = h0[idx];
        hf[idx] = v;
        u16 h, m; split2(v, h, m);
        hp[idx] = h; hp[PL_H + idx] = m;
    }
}

// ---------------- host ----------------
extern "C" void kernel_launch(void* const* d_in, const int* in_sizes, int n_in,
                              void* d_out, int out_size, void* d_ws, size_t ws_size,
                              hipStream_t stream) {
    (void)in_sizes; (void)n_in; (void)out_size; (void)ws_size;
    const float* x    = (const float*)d_in[0];
    const float* mem0 = (const float*)d_in[1];
    const float* wr0  = (const float*)d_in[2];
    const float* ww0  = (const float*)d_in[3];
    const float* h0   = (const float*)d_in[4];
    const float* Wx   = (const float*)d_in[5];
    const float* Wr   = (const float*)d_in[6];
    const float* bh   = (const float*)d_in[7];
    const float* Whr  = (const float*)d_in[8];
    const float* bhr  = (const float*)d_in[9];
    const float* Whw  = (const float*)d_in[10];
    const float* bhw  = (const float*)d_in[11];
    const float* Wea  = (const float*)d_in[12];
    const float* bea  = (const float*)d_in[13];
    const float* Wo   = (const float*)d_in[14];
    const float* bo   = (const float*)d_in[15];
    float* out = (float*)d_out;

    char* wsb = (char*)d_ws;
    size_t off = 0;
    auto carveU = [&](size_t elems) { u16* p = (u16*)(wsb + off); off += elems * sizeof(u16); return p; };
    u16* BigT    = carveU(2 * (size_t)PL_BIG);
    u16* WxT     = carveU(2 * (size_t)PL_WXT);
    u16* WrT     = carveU(2 * (size_t)PL_WRT);
    u16* mem_pl  = carveU(2 * (size_t)PL_MEM);
    u16* memT_pl = carveU(2 * (size_t)PL_MEM);
    u16* wwT_pl  = carveU(2 * (size_t)PL_W);
    u16* wr_pl   = carveU(2 * (size_t)PL_W);
    u16* h_pl    = carveU(2 * (size_t)PL_H);
    u16* r_pl    = carveU(2 * (size_t)PL_H);
    u16* eT_pl   = carveU(2 * (size_t)PL_H);
    u16* aT_pl   = carveU(2 * (size_t)PL_H);
    u16* kh_pl   = carveU(2 * (size_t)PL_KH);
    auto carveF = [&](size_t elems) { float* p = (float*)(wsb + off); off += elems * sizeof(float); return p; };
    float* memf   = carveF((size_t)N_ * M_);
    float* wwf    = carveF((size_t)B_ * N_);
    float* wrf    = carveF((size_t)B_ * N_);
    float* hf     = carveF((size_t)B_ * H_);
    float* logits = carveF((size_t)2 * B_ * N_);
    float* ssqp   = carveF((size_t)N_ * 8);
    float* w6w    = carveF(H_ * 6);
    float* w6r    = carveF(H_ * 6);
    // barrier region: NB_ slots (64B apart) + flag on its own line
    off = (off + 127) & ~(size_t)127;
    unsigned* slots = (unsigned*)(wsb + off);           // slots[NB_*16]
    unsigned* flag  = slots + NB_ * 16;                 // 64B-aligned
    off += (NB_ * 16 + 16) * sizeof(unsigned) + 64;

    // ---- prologue: weight decomposition + state init (also zeroes the barrier region) ----
    decomp_t<<<dim3(16, 16), 256, 0, stream>>>(Whw, M_ + 6, 0, 512, BigT, PL_BIG);                       // rows 0-511
    decomp_t<<<dim3(16, 16), 256, 0, stream>>>(Whr, M_ + 6, 0, 512, BigT + (size_t)512 * 512, PL_BIG);   // rows 512-1023
    decomp_t<<<dim3(16, 16), 256, 0, stream>>>(Wo, 512, 0, 512, BigT + (size_t)1024 * 512, PL_BIG);      // rows 1024-1535
    decomp_t<<<dim3(16, 32), 256, 0, stream>>>(Wea, 1024, 0, 512, BigT + (size_t)1536 * 512, PL_BIG);    // rows 1536-2559
    decomp_t<<<dim3(16, 16), 256, 0, stream>>>(Wx, 512, 0, 512, WxT, PL_WXT);
    decomp_t<<<dim3(16, 16), 256, 0, stream>>>(Wr, 512, 0, 512, WrT, PL_WRT);
    wh6_kernel<<<2, 512, 0, stream>>>(Whw, Whr, w6w, w6r, slots);
    init_mem<<<N_, 256, 0, stream>>>(mem0, memf, mem_pl, memT_pl);
    init_w<<<B_, 256, 0, stream>>>(wr0, ww0, wrf, wwf, wr_pl, wwT_pl);
    init_h<<<B_, 64, 0, stream>>>(h0, hf, h_pl);
    // xwx for all (t,b) -> stored in d_out slots [b][t][:]
    gemm2_xwx<<<dim3(8, 512), 256, 0, stream>>>(x, WxT, out);
    // ea for step 0 from h0
    gemm2<32, EpiEA0><<<dim3(16, 8), 256, 0, stream>>>(
        h_pl, 512, PL_H, BigT + (size_t)1536 * 512, 512, PL_BIG, 512, EpiEA0{bea, eT_pl, aT_pl});

    // ---- the entire T-loop: one persistent kernel, fence-free, BK=64 + phase overlap ----
    NtmArgs A;
    A.BigT = BigT; A.WxT = WxT; A.WrT = WrT;
    A.mem_pl = mem_pl; A.memT_pl = memT_pl; A.wwT_pl = wwT_pl; A.wr_pl = wr_pl;
    A.h_pl = h_pl; A.r_pl = r_pl; A.eT_pl = eT_pl; A.aT_pl = aT_pl; A.kh_pl = kh_pl;
    A.memf = memf; A.wwf = wwf; A.wrf = wrf; A.hf = hf; A.logits = logits; A.ssqp = ssqp;
    A.w6w = w6w; A.w6r = w6r; A.bh = bh; A.bhw = bhw; A.bhr = bhr; A.bea = bea; A.bo = bo;
    A.out = out;
    A.slots = slots;
    A.flag = flag;
    ntm_loop<<<dim3(NB_), dim3(256), 0, stream>>>(A);
}

// Round 9
// 18097.215 us; speedup vs baseline: 1.4411x; 1.4411x over previous
//
#include <hip/hip_runtime.h>
#include <math.h>

// NTM recurrence. GEMMs via 3-product 2-plane bf16-split MFMA (~2^-17 rel err per GEMM,
// fp32 state masters). T-loop inside ONE persistent kernel (512 blocks, 2/CU co-resident).
// Coherence (r4/r7 scheme): NO cache fences. Mutable cross-block data via relaxed agent-scope
// (sc1) accesses (8B loads, write-through stores); read-only weights normal-cached (L2-resident
// forever). r9 = r7 + ONE change: BK=64 for P2/P3/P5 (iters 32/16/16 -> 16/8/8; critical path
// 88 -> 56 K-iters/step). P4 kept byte-identical to r7 (r8's P4b swizzle broke XCD locality:
// bx period 12 vs XCD period 8 -> +17MB/step L2-miss refetch -> 26ms regression).
// B=256 T=128 I=512 H=512 N=1024 M=512 O=512
#define B_ 256
#define T_ 128
#define I_ 512
#define H_ 512
#define N_ 1024
#define M_ 512
#define O_ 512
#define EPS_ 1e-8f
#define NB_ 512  // persistent grid: 512 blocks x 256 thr, 2 blocks/CU co-resident

typedef unsigned short u16;
typedef unsigned long long u64;
typedef __attribute__((ext_vector_type(8))) short v8s;   // 8 bf16 = 4 VGPRs
typedef __attribute__((ext_vector_type(4))) float v4f;   // MFMA acc

#define MFMA(a, b, c) __builtin_amdgcn_mfma_f32_16x16x32_bf16(a, b, c, 0, 0, 0)

// plane strides (elements)
#define PL_BIG 1310720  // BigT [2560][512]: rows 0-511 Whw_k, 512-1023 Whr_k, 1024-1535 Wo, 1536-2559 Wea
#define PL_WXT 262144   // WxT  [512][512]
#define PL_WRT 262144   // WrT  [512][512]
#define PL_MEM 524288   // mem  [1024][512] / memT [512][1024]
#define PL_W   262144   // wwT [1024][256] / wr [256][1024]
#define PL_H   131072   // h [256][512], r [256][512], eT/aT [512][256]
#define PL_KH  262144   // kh [512][512]

// ---------------- sc1 (agent-coherent) access helpers ----------------
template <typename T>
__device__ __forceinline__ T lda_(const T* p) {
    return __hip_atomic_load(const_cast<T*>(p), __ATOMIC_RELAXED, __HIP_MEMORY_SCOPE_AGENT);
}
template <typename T>
__device__ __forceinline__ void sta_(T* p, T v) {
    __hip_atomic_store(p, v, __ATOMIC_RELAXED, __HIP_MEMORY_SCOPE_AGENT);
}
__device__ __forceinline__ uint4 ld16_(const u16* p) {  // 16B as 2 x dwordx2 sc1
    const u64* q = (const u64*)p;
    u64 lo = __hip_atomic_load(const_cast<u64*>(q), __ATOMIC_RELAXED, __HIP_MEMORY_SCOPE_AGENT);
    u64 hi = __hip_atomic_load(const_cast<u64*>(q + 1), __ATOMIC_RELAXED, __HIP_MEMORY_SCOPE_AGENT);
    uint4 r;
    r.x = (unsigned)lo; r.y = (unsigned)(lo >> 32);
    r.z = (unsigned)hi; r.w = (unsigned)(hi >> 32);
    return r;
}
__device__ __forceinline__ void st64_(u16* p, u16 a, u16 b, u16 c, u16 d) {
    u64 v = (u64)a | ((u64)b << 16) | ((u64)c << 32) | ((u64)d << 48);
    __hip_atomic_store((u64*)p, v, __ATOMIC_RELAXED, __HIP_MEMORY_SCOPE_AGENT);
}

// ---------------- scalar helpers ----------------
__device__ __forceinline__ float sigm_(float x) { return 1.f / (1.f + expf(-x)); }
__device__ __forceinline__ float softplus_(float x) { return x > 20.f ? x : log1pf(expf(x)); }
__device__ __forceinline__ u16 f2bf(float f) {
    unsigned u = __float_as_uint(f);
    u += 0x7fffu + ((u >> 16) & 1u);
    return (u16)(u >> 16);
}
__device__ __forceinline__ float bf2f(u16 h) { return __uint_as_float((unsigned)h << 16); }
__device__ __forceinline__ void split2(float f, u16& h, u16& m) {
    h = f2bf(f);
    m = f2bf(f - bf2f(h));
}

__device__ __forceinline__ float wave_sum_(float v) {
#pragma unroll
    for (int o = 32; o > 0; o >>= 1) v += __shfl_down(v, o);
    return v;
}
__device__ __forceinline__ float wave_max_(float v) {
#pragma unroll
    for (int o = 32; o > 0; o >>= 1) v = fmaxf(v, __shfl_down(v, o));
    return v;
}
__device__ float block_sum_(float v, float* s) {
    int lane = threadIdx.x & 63, wid = threadIdx.x >> 6, nw = blockDim.x >> 6;
    v = wave_sum_(v);
    if (lane == 0) s[wid] = v;
    __syncthreads();
    float r = (threadIdx.x < nw) ? s[threadIdx.x] : 0.f;
    if (wid == 0) { r = wave_sum_(r); if (lane == 0) s[0] = r; }
    __syncthreads();
    float out = s[0];
    __syncthreads();
    return out;
}
__device__ float block_max_(float v, float* s) {
    int lane = threadIdx.x & 63, wid = threadIdx.x >> 6, nw = blockDim.x >> 6;
    v = wave_max_(v);
    if (lane == 0) s[wid] = v;
    __syncthreads();
    float r = (threadIdx.x < nw) ? s[threadIdx.x] : -3.4e38f;
    if (wid == 0) { r = wave_max_(r); if (lane == 0) s[0] = r; }
    __syncthreads();
    float out = s[0];
    __syncthreads();
    return out;
}

// ---------------- grid barrier: per-block slots + release flag, NO fences ----------------
__device__ __forceinline__ void gsync(unsigned* slots, unsigned* flag, unsigned epoch) {
    __syncthreads();
    if (threadIdx.x == 0)
        __hip_atomic_store(&slots[blockIdx.x * 16], epoch, __ATOMIC_RELAXED,
                           __HIP_MEMORY_SCOPE_AGENT);
    if (blockIdx.x == 0) {
        while (__hip_atomic_load(&slots[threadIdx.x * 16], __ATOMIC_RELAXED,
                                 __HIP_MEMORY_SCOPE_AGENT) < epoch)
            __builtin_amdgcn_s_sleep(1);
        while (__hip_atomic_load(&slots[(threadIdx.x + 256) * 16], __ATOMIC_RELAXED,
                                 __HIP_MEMORY_SCOPE_AGENT) < epoch)
            __builtin_amdgcn_s_sleep(1);
        __syncthreads();  // all 512 slots arrived
        if (threadIdx.x == 0)
            __hip_atomic_store(flag, epoch, __ATOMIC_RELAXED, __HIP_MEMORY_SCOPE_AGENT);
    } else if (threadIdx.x == 0) {
        while (__hip_atomic_load(flag, __ATOMIC_RELAXED, __HIP_MEMORY_SCOPE_AGENT) < epoch)
            __builtin_amdgcn_s_sleep(1);
    }
    __syncthreads();
}

// ---------------- epilogues (per 16x16 fragment: rows r0..r0+3 (A-rows), col c (B-row)) ----------------
struct EpiEA0 {  // prologue ea only (separate kernel launch -> plain stores OK): r=b, c=m
    const float* bea; u16* eT; u16* aT;
    __device__ void operator()(int r0, int c, v4f v) const {
#pragma unroll
        for (int r = 0; r < 4; r++) {
            float val = v[r] + bea[c];
            u16* dst;
            int b = r0 + r;
            if (c < M_) { val = sigm_(val); dst = eT + (size_t)c * B_ + b; }
            else        { val = tanhf(val); dst = aT + (size_t)(c - M_) * B_ + b; }
            u16 h, m; split2(val, h, m);
            dst[0] = h; dst[PL_H] = m;
        }
    }
};
struct EpiR {  // C[b][m] -> r planes (sc1)
    u16* rp;
    __device__ void operator()(int r0, int c, v4f v) const {
#pragma unroll
        for (int r = 0; r < 4; r++) {
            u16 h, m; split2(v[r], h, m);
            size_t idx = (size_t)(r0 + r) * M_ + c;
            sta_(rp + idx, h); sta_(rp + PL_H + idx, m);
        }
    }
};
struct EpiH {  // C[b][hdim] + xwx(in d_out layout, cached read) + bh -> tanh -> h (sc1)
    const float* xwxt; const float* bh; float* hf; u16* hp;
    __device__ void operator()(int r0, int c, v4f v) const {
#pragma unroll
        for (int r = 0; r < 4; r++) {
            int b = r0 + r;
            float val = tanhf(v[r] + xwxt[(size_t)b * (T_ * O_) + c] + bh[c]);
            size_t idx = (size_t)b * H_ + c;
            sta_(hf + idx, val);
            u16 h, m; split2(val, h, m);
            sta_(hp + idx, h); sta_(hp + PL_H + idx, m);
        }
    }
};
struct EpiFused {  // c<1024: keys; 1024..1535: out; 1536..: ea(next step)
    const float* bhw; const float* bhr; const float* bo; const float* bea;
    u16* khp; float* outt; u16* eT; u16* aT;
    __device__ void operator()(int r0, int c, v4f v) const {
        if (c < 1024) {
            int head = c >> 9, key = c & 511;
            const float* bb = head ? bhr : bhw;
#pragma unroll
            for (int r = 0; r < 4; r++) {
                float val = tanhf(v[r] + bb[key]);
                size_t idx = (size_t)(head * 256 + r0 + r) * M_ + key;
                u16 h, m; split2(val, h, m);
                sta_(khp + idx, h); sta_(khp + PL_KH + idx, m);
            }
        } else if (c < 1536) {
            int o = c - 1024;
#pragma unroll
            for (int r = 0; r < 4; r++)
                outt[(size_t)(r0 + r) * (T_ * O_) + o] = sigm_(v[r] + bo[o]);  // host-read only
        } else {
            int m = c - 1536;
#pragma unroll
            for (int r = 0; r < 4; r++) {
                float val = v[r] + bea[m];
                u16* dst;
                int b = r0 + r;
                if (m < M_) { val = sigm_(val); dst = eT + (size_t)m * B_ + b; }
                else        { val = tanhf(val); dst = aT + (size_t)(m - M_) * B_ + b; }
                u16 h, mm; split2(val, h, mm);
                sta_(dst, h); sta_(dst + PL_H, mm);
            }
        }
    }
};

// ---------------- persistent-kernel args ----------------
struct NtmArgs {
    const u16 *BigT, *WxT, *WrT;
    u16 *mem_pl, *memT_pl, *wwT_pl, *wr_pl, *h_pl, *r_pl, *eT_pl, *aT_pl, *kh_pl;
    float *memf, *wwf, *wrf, *hf, *logits, *ssqp;
    const float *w6w, *w6r, *bh, *bhw, *bhr, *bea, *bo;
    float* out;
    unsigned* slots;
    unsigned* flag;
};

// ---------------- device: 3-product MFMA GEMM tile 32x64, BK=32 (phase 4; r7-proven) ----------------
template <bool AS, bool BS, class Epi>
__device__ __forceinline__ void dev_gemm32(char* smc, const u16* __restrict__ Ap, int lda, int apl,
                                           const u16* __restrict__ Bp, int ldb, int bpl,
                                           int K, int row0, int col0, const Epi& epi) {
    typedef u16 (*AsT)[32][40];
    typedef u16 (*BsT)[64][40];
    AsT As = (AsT)smc;            // [2][32][40] = 5120 B
    BsT Bs = (BsT)(smc + 5120);   // [2][64][40] = 10240 B
    const int tid = threadIdx.x, lane = tid & 63, w = tid >> 6;
    const int wy = w >> 1, wx = w & 1, q = lane >> 4, l15 = lane & 15;
    uint4 ra, rb[2];
    auto loadA = [&](int k0) {
        int s = tid, p = s >> 7, rr = (s >> 2) & 31, kg = s & 3;
        const u16* ap = Ap + (size_t)p * apl + (size_t)(row0 + rr) * lda + k0 + kg * 8;
        ra = AS ? ld16_(ap) : *(const uint4*)ap;
    };
    auto loadB = [&](int k0) {
#pragma unroll
        for (int j = 0; j < 2; j++) {
            int s = j * 256 + tid, p = s >> 8, rr = (s >> 2) & 63, kg = s & 3;
            const u16* bp = Bp + (size_t)p * bpl + (size_t)(col0 + rr) * ldb + k0 + kg * 8;
            rb[j] = BS ? ld16_(bp) : *(const uint4*)bp;
        }
    };
    v4f acc[2] = {};
    loadA(0); loadB(0);
    for (int k0 = 0; k0 < K; k0 += 32) {
        {
            int s = tid, p = s >> 7, rr = (s >> 2) & 31, kg = s & 3;
            *(uint4*)&As[p][rr][kg * 8] = ra;
        }
#pragma unroll
        for (int j = 0; j < 2; j++) {
            int s = j * 256 + tid, p = s >> 8, rr = (s >> 2) & 63, kg = s & 3;
            *(uint4*)&Bs[p][rr][kg * 8] = rb[j];
        }
        __syncthreads();
        if (k0 + 32 < K) { loadA(k0 + 32); loadB(k0 + 32); }
        v8s af0 = *(const v8s*)&As[0][wy * 16 + l15][q * 8];
        v8s af1 = *(const v8s*)&As[1][wy * 16 + l15][q * 8];
        v8s bf[2][2];
#pragma unroll
        for (int nt = 0; nt < 2; nt++) {
            bf[nt][0] = *(const v8s*)&Bs[0][wx * 32 + nt * 16 + l15][q * 8];
            bf[nt][1] = *(const v8s*)&Bs[1][wx * 32 + nt * 16 + l15][q * 8];
        }
#pragma unroll
        for (int nt = 0; nt < 2; nt++) {
            v4f c = acc[nt];
            c = MFMA(af0, bf[nt][0], c);
            c = MFMA(af0, bf[nt][1], c);
            c = MFMA(af1, bf[nt][0], c);
            acc[nt] = c;
        }
        __syncthreads();
    }
#pragma unroll
    for (int nt = 0; nt < 2; nt++)
        epi(row0 + wy * 16 + q * 4, col0 + wx * 32 + nt * 16 + l15, acc[nt]);
}

// ---------------- device: 3-product MFMA GEMM tile 64x64, BK=64 (phases 2,3) ----------------
template <bool AS, bool BS, class Epi>
__device__ __forceinline__ void dev_g64(char* smc, const u16* __restrict__ Ap, int lda, int apl,
                                        const u16* __restrict__ Bp, int ldb, int bpl,
                                        int K, int row0, int col0, const Epi& epi) {
    typedef u16 (*T72)[64][72];
    T72 As = (T72)smc;             // 18432 B
    T72 Bs = (T72)(smc + 18432);   // 18432 B
    const int tid = threadIdx.x, lane = tid & 63, w = tid >> 6;
    const int wy = w >> 1, wx = w & 1, q = lane >> 4, l15 = lane & 15;
    uint4 ra[4], rb[4];
    auto loadA = [&](int k0) {
#pragma unroll
        for (int j = 0; j < 4; j++) {
            int s = j * 256 + tid, p = s >> 9, rr = (s >> 3) & 63, kg = s & 7;
            const u16* ap = Ap + (size_t)p * apl + (size_t)(row0 + rr) * lda + k0 + kg * 8;
            ra[j] = AS ? ld16_(ap) : *(const uint4*)ap;
        }
    };
    auto loadB = [&](int k0) {
#pragma unroll
        for (int j = 0; j < 4; j++) {
            int s = j * 256 + tid, p = s >> 9, rr = (s >> 3) & 63, kg = s & 7;
            const u16* bp = Bp + (size_t)p * bpl + (size_t)(col0 + rr) * ldb + k0 + kg * 8;
            rb[j] = BS ? ld16_(bp) : *(const uint4*)bp;
        }
    };
    v4f acc[2][2] = {};
    loadA(0); loadB(0);
    for (int k0 = 0; k0 < K; k0 += 64) {
#pragma unroll
        for (int j = 0; j < 4; j++) {
            int s = j * 256 + tid, p = s >> 9, rr = (s >> 3) & 63, kg = s & 7;
            *(uint4*)&As[p][rr][kg * 8] = ra[j];
            *(uint4*)&Bs[p][rr][kg * 8] = rb[j];
        }
        __syncthreads();
        if (k0 + 64 < K) { loadA(k0 + 64); loadB(k0 + 64); }
        v8s af[2][2][2], bf[2][2][2];  // [mt|nt][plane][k-half]
#pragma unroll
        for (int mt = 0; mt < 2; mt++)
#pragma unroll
            for (int p = 0; p < 2; p++)
#pragma unroll
                for (int h = 0; h < 2; h++) {
                    af[mt][p][h] = *(const v8s*)&As[p][wy * 32 + mt * 16 + l15][h * 32 + q * 8];
                    bf[mt][p][h] = *(const v8s*)&Bs[p][wx * 32 + mt * 16 + l15][h * 32 + q * 8];
                }
#pragma unroll
        for (int mt = 0; mt < 2; mt++)
#pragma unroll
            for (int nt = 0; nt < 2; nt++) {
                v4f c = acc[mt][nt];
#pragma unroll
                for (int h = 0; h < 2; h++) {
                    c = MFMA(af[mt][0][h], bf[nt][0][h], c);
                    c = MFMA(af[mt][0][h], bf[nt][1][h], c);
                    c = MFMA(af[mt][1][h], bf[nt][0][h], c);
                }
                acc[mt][nt] = c;
            }
        __syncthreads();
    }
#pragma unroll
    for (int mt = 0; mt < 2; mt++)
#pragma unroll
        for (int nt = 0; nt < 2; nt++)
            epi(row0 + wy * 32 + mt * 16 + q * 4, col0 + wx * 32 + nt * 16 + l15, acc[mt][nt]);
}

// ---------------- device: memupd (BK=32, known-good; Se/Sa + mem update + row ssq) ----------------
__device__ void dev_memupd(char* smc, int bid, const NtmArgs& A) {
    typedef u16 (*T64)[64][40];
    T64 As = (T64)smc;                 // 10240 B
    T64 Be = (T64)(smc + 10240);
    T64 Ba = (T64)(smc + 20480);
    float* ssqs = (float*)(smc + 30720);
    const int tid = threadIdx.x, lane = tid & 63, w = tid >> 6;
    const int wy = w >> 1, wx = w & 1, q = lane >> 4, l15 = lane & 15;
    const int bx = bid & 7, by = bid >> 3;
    const int row0 = by * 64, col0 = bx * 64;  // row=n, col=m
    if (tid < 64) ssqs[tid] = 0.f;
    uint4 rA[2], rE[2], rB[2];
    auto loadAll = [&](int k0) {
#pragma unroll
        for (int j = 0; j < 2; j++) {
            int s = j * 256 + tid, p = s >> 8, rr = (s >> 2) & 63, kg = s & 3;
            rA[j] = ld16_(A.wwT_pl + (size_t)p * PL_W + (size_t)(row0 + rr) * B_ + k0 + kg * 8);
            rE[j] = ld16_(A.eT_pl + (size_t)p * PL_H + (size_t)(col0 + rr) * B_ + k0 + kg * 8);
            rB[j] = ld16_(A.aT_pl + (size_t)p * PL_H + (size_t)(col0 + rr) * B_ + k0 + kg * 8);
        }
    };
    v4f ae[2][2] = {}, aa[2][2] = {};
    loadAll(0);
    for (int k0 = 0; k0 < B_; k0 += 32) {
#pragma unroll
        for (int j = 0; j < 2; j++) {
            int s = j * 256 + tid, p = s >> 8, rr = (s >> 2) & 63, kg = s & 3;
            *(uint4*)&As[p][rr][kg * 8] = rA[j];
            *(uint4*)&Be[p][rr][kg * 8] = rE[j];
            *(uint4*)&Ba[p][rr][kg * 8] = rB[j];
        }
        __syncthreads();
        if (k0 + 32 < B_) loadAll(k0 + 32);
        v8s af[2][2], be[2][2], ba[2][2];
#pragma unroll
        for (int mt = 0; mt < 2; mt++) {
            af[mt][0] = *(const v8s*)&As[0][wy * 32 + mt * 16 + l15][q * 8];
            af[mt][1] = *(const v8s*)&As[1][wy * 32 + mt * 16 + l15][q * 8];
            be[mt][0] = *(const v8s*)&Be[0][wx * 32 + mt * 16 + l15][q * 8];
            be[mt][1] = *(const v8s*)&Be[1][wx * 32 + mt * 16 + l15][q * 8];
            ba[mt][0] = *(const v8s*)&Ba[0][wx * 32 + mt * 16 + l15][q * 8];
            ba[mt][1] = *(const v8s*)&Ba[1][wx * 32 + mt * 16 + l15][q * 8];
        }
#pragma unroll
        for (int mt = 0; mt < 2; mt++)
#pragma unroll
            for (int nt = 0; nt < 2; nt++) {
                v4f c = ae[mt][nt];
                c = MFMA(af[mt][0], be[nt][0], c);
                c = MFMA(af[mt][0], be[nt][1], c);
                c = MFMA(af[mt][1], be[nt][0], c);
                ae[mt][nt] = c;
                v4f d = aa[mt][nt];
                d = MFMA(af[mt][0], ba[nt][0], d);
                d = MFMA(af[mt][0], ba[nt][1], d);
                d = MFMA(af[mt][1], ba[nt][0], d);
                aa[mt][nt] = d;
            }
        __syncthreads();
    }
    const float invB = 1.f / (float)B_;
#pragma unroll
    for (int mt = 0; mt < 2; mt++)
#pragma unroll
        for (int nt = 0; nt < 2; nt++) {
            int r0 = row0 + wy * 32 + mt * 16 + q * 4;
            int c  = col0 + wx * 32 + nt * 16 + l15;
            u16 hv[4][2];
#pragma unroll
            for (int r = 0; r < 4; r++) {
                size_t idx = (size_t)(r0 + r) * M_ + c;
                float old = A.memf[idx];  // block-private tile (same block every step): cached
                float nv = old * (1.f - ae[mt][nt][r] * invB) + aa[mt][nt][r] * invB;
                A.memf[idx] = nv;
                u16 h, m; split2(nv, h, m);
                sta_(A.mem_pl + idx, h); sta_(A.mem_pl + PL_MEM + idx, m);
                hv[r][0] = h; hv[r][1] = m;
                atomicAdd(&ssqs[r0 + r - row0], nv * nv);
            }
            size_t tb = (size_t)c * N_ + r0;
            st64_(A.memT_pl + tb, hv[0][0], hv[1][0], hv[2][0], hv[3][0]);
            st64_(A.memT_pl + PL_MEM + tb, hv[0][1], hv[1][1], hv[2][1], hv[3][1]);
        }
    __syncthreads();
    if (tid < 64) sta_(A.ssqp + (size_t)(row0 + tid) * 8 + bx, ssqs[tid]);
}

// ---------------- device: logits = (kh @ mem^T) * invn  (64x64, BK=64) ----------------
__device__ void dev_logits(char* smc, int bx, int by, const NtmArgs& A) {
    typedef u16 (*T72)[64][72];
    T72 As = (T72)smc;
    T72 Bs = (T72)(smc + 18432);
    float* invn_s = (float*)(smc + 36864);
    const int tid = threadIdx.x, lane = tid & 63, w = tid >> 6;
    const int wy = w >> 1, wx = w & 1, q = lane >> 4, l15 = lane & 15;
    const int row0 = by * 64, col0 = bx * 64;  // row in [0,512), col=n
    if (tid < 64) {
        float s = 0.f;
#pragma unroll
        for (int j = 0; j < 8; j++) s += lda_(A.ssqp + (size_t)(col0 + tid) * 8 + j);
        invn_s[tid] = 1.f / (sqrtf(s) + EPS_);
    }
    uint4 ra[4], rb[4];
    auto loadAll = [&](int k0) {
#pragma unroll
        for (int j = 0; j < 4; j++) {
            int s = j * 256 + tid, p = s >> 9, rr = (s >> 3) & 63, kg = s & 7;
            ra[j] = ld16_(A.kh_pl + (size_t)p * PL_KH + (size_t)(row0 + rr) * M_ + k0 + kg * 8);
            rb[j] = ld16_(A.mem_pl + (size_t)p * PL_MEM + (size_t)(col0 + rr) * M_ + k0 + kg * 8);
        }
    };
    v4f acc[2][2] = {};
    loadAll(0);
    for (int k0 = 0; k0 < M_; k0 += 64) {
#pragma unroll
        for (int j = 0; j < 4; j++) {
            int s = j * 256 + tid, p = s >> 9, rr = (s >> 3) & 63, kg = s & 7;
            *(uint4*)&As[p][rr][kg * 8] = ra[j];
            *(uint4*)&Bs[p][rr][kg * 8] = rb[j];
        }
        __syncthreads();
        if (k0 + 64 < M_) loadAll(k0 + 64);
        v8s af[2][2][2], bf[2][2][2];
#pragma unroll
        for (int mt = 0; mt < 2; mt++)
#pragma unroll
            for (int p = 0; p < 2; p++)
#pragma unroll
                for (int h = 0; h < 2; h++) {
                    af[mt][p][h] = *(const v8s*)&As[p][wy * 32 + mt * 16 + l15][h * 32 + q * 8];
                    bf[mt][p][h] = *(const v8s*)&Bs[p][wx * 32 + mt * 16 + l15][h * 32 + q * 8];
                }
#pragma unroll
        for (int mt = 0; mt < 2; mt++)
#pragma unroll
            for (int nt = 0; nt < 2; nt++) {
                v4f c = acc[mt][nt];
#pragma unroll
                for (int h = 0; h < 2; h++) {
                    c = MFMA(af[mt][0][h], bf[nt][0][h], c);
                    c = MFMA(af[mt][0][h], bf[nt][1][h], c);
                    c = MFMA(af[mt][1][h], bf[nt][0][h], c);
                }
                acc[mt][nt] = c;
            }
        __syncthreads();
    }
#pragma unroll
    for (int mt = 0; mt < 2; mt++)
#pragma unroll
        for (int nt = 0; nt < 2; nt++) {
            int r0 = row0 + wy * 32 + mt * 16 + q * 4;
            int c  = col0 + wx * 32 + nt * 16 + l15;
            float in_ = invn_s[c - col0];
#pragma unroll
            for (int r = 0; r < 4; r++)
                sta_(A.logits + (size_t)(r0 + r) * N_ + c, acc[mt][nt][r] * in_);
        }
}

// ---------------- device: addressing tail ----------------
__device__ void dev_addr(char* smc, int row, const NtmArgs& A) {
    float* wgs = (float*)smc;           // N_ floats = 4096 B
    float* red = (float*)(smc + 4096);  // 8 floats
    int head = row >> 8, b = row & 255;
    const float* w6 = head ? A.w6r : A.w6w;
    const float* bias = head ? A.bhr : A.bhw;
    float* wf = head ? A.wrf : A.wwf;   // master row b: exclusively owned by this block
    int tid = threadIdx.x;
    float d0 = 0, d1 = 0, d2 = 0, d3 = 0, d4 = 0, d5 = 0, ssq = 0;
#pragma unroll
    for (int j = 0; j < 2; j++) {
        int k = tid + j * 256;
        float hv = lda_(A.hf + (size_t)b * H_ + k);
        const float* wk = w6 + k * 6;
        d0 += hv * wk[0]; d1 += hv * wk[1]; d2 += hv * wk[2];
        d3 += hv * wk[3]; d4 += hv * wk[4]; d5 += hv * wk[5];
        size_t ki = (size_t)row * M_ + k;
        float kv = bf2f(lda_(A.kh_pl + ki)) + bf2f(lda_(A.kh_pl + PL_KH + ki));
        ssq += kv * kv;
    }
    d0 = block_sum_(d0, red); d1 = block_sum_(d1, red); d2 = block_sum_(d2, red);
    d3 = block_sum_(d3, red); d4 = block_sum_(d4, red); d5 = block_sum_(d5, red);
    ssq = block_sum_(ssq, red);
    float beta = softplus_(d0 + bias[M_]);
    float g = sigm_(d1 + bias[M_ + 1]);
    float a0 = d2 + bias[M_ + 2], a1 = d3 + bias[M_ + 3], a2 = d4 + bias[M_ + 4];
    float mx3 = fmaxf(a0, fmaxf(a1, a2));
    float e0 = expf(a0 - mx3), e1 = expf(a1 - mx3), e2 = expf(a2 - mx3);
    float es = e0 + e1 + e2;
    float s0 = e0 / es, s1 = e1 / es, s2 = e2 / es;
    float gamma = 1.f + softplus_(d5 + bias[M_ + 5]);
    float rowsc = beta / (sqrtf(ssq) + EPS_);
    const u64* lp = (const u64*)(A.logits + (size_t)row * N_ + tid * 4);
    u64 la = lda_(lp), lb = lda_(lp + 1);
    float l[4];
    l[0] = __uint_as_float((unsigned)la) * rowsc;
    l[1] = __uint_as_float((unsigned)(la >> 32)) * rowsc;
    l[2] = __uint_as_float((unsigned)lb) * rowsc;
    l[3] = __uint_as_float((unsigned)(lb >> 32)) * rowsc;
    float mx = fmaxf(fmaxf(l[0], l[1]), fmaxf(l[2], l[3]));
    mx = block_max_(mx, red);
    float ex[4], sum = 0.f;
#pragma unroll
    for (int j = 0; j < 4; j++) { ex[j] = expf(l[j] - mx); sum += ex[j]; }
    sum = block_sum_(sum, red);
    float inv = 1.f / sum;
    float wprev[4];
#pragma unroll
    for (int j = 0; j < 4; j++) wprev[j] = wf[(size_t)b * N_ + tid * 4 + j];
#pragma unroll
    for (int j = 0; j < 4; j++) wgs[tid * 4 + j] = g * ex[j] * inv + (1.f - g) * wprev[j];
    __syncthreads();
    float wp[4], psum = 0.f;
#pragma unroll
    for (int j = 0; j < 4; j++) {
        int n = tid * 4 + j;
        float wt = s0 * wgs[(n + 1) & (N_ - 1)] + s1 * wgs[n] + s2 * wgs[(n - 1) & (N_ - 1)];
        float v = expf(gamma * logf(wt));
        wp[j] = v; psum += v;
    }
    psum = block_sum_(psum, red);
    float invp = 1.f / (psum + EPS_);
#pragma unroll
    for (int j = 0; j < 4; j++) {
        int n = tid * 4 + j;
        float val = wp[j] * invp;
        wf[(size_t)b * N_ + n] = val;  // block-private master: cached
        u16 h, m; split2(val, h, m);
        if (head == 0) {
            size_t tb = (size_t)n * B_ + b;
            sta_(A.wwT_pl + tb, h); sta_(A.wwT_pl + PL_W + tb, m);
        } else {
            size_t idx = (size_t)b * N_ + n;
            sta_(A.wr_pl + idx, h); sta_(A.wr_pl + PL_W + idx, m);
        }
    }
}

// ---------------- persistent kernel: the whole T-loop ----------------
__global__ __launch_bounds__(256, 2) void ntm_loop(NtmArgs A) {
    __shared__ __align__(16) char sm[37120];
    const int bid = blockIdx.x;
    unsigned ep = 0;
    for (int t = 0; t < T_; t++) {
        // 1. mem update + row-ssq partials  [n x m, K=256]  (128 tiles 64x64, BK=32 -> 8 iters)
        if (bid < 128) dev_memupd(sm, bid, A);
        gsync(A.slots, A.flag, ++ep);
        // 2. r = wr @ mem  [256 x 512, K=1024]  (32 tiles 64x64, BK=64 -> 16 iters)
        if (bid < 32) {
            int bx = bid & 7, by = bid >> 3;
            dev_g64<true, true>(sm, A.wr_pl, 1024, PL_W, A.memT_pl, 1024, PL_MEM, 1024,
                                by * 64, bx * 64, EpiR{A.r_pl});
        }
        gsync(A.slots, A.flag, ++ep);
        // 3. h = tanh(xwx + r @ Wr + bh)  [256 x 512, K=512]  (32 tiles 64x64, BK=64 -> 8 iters)
        if (bid < 32) {
            int bx = bid & 7, by = bid >> 3;
            dev_g64<true, false>(sm, A.r_pl, 512, PL_H, A.WrT, 512, PL_WRT, 512,
                                 by * 64, bx * 64,
                                 EpiH{A.out + (size_t)t * O_, A.bh, A.hf, A.h_pl});
        }
        gsync(A.slots, A.flag, ++ep);
        // 4. fused: h @ [Whw_k | Whr_k | Wo | Wea]  (320 tiles 32x64; r7-proven g*5 XCD swizzle)
        if (bid < 320) {
            int g = bid & 7, idx = bid >> 3;           // idx 0..39
            int bx = g * 5 + idx % 5, by = idx / 5;    // bx 0..39, by 0..7
            dev_gemm32<true, false>(sm, A.h_pl, 512, PL_H, A.BigT, 512, PL_BIG, 512,
                                    by * 32, bx * 64,
                                    EpiFused{A.bhw, A.bhr, A.bo, A.bea, A.kh_pl,
                                             A.out + (size_t)t * O_, A.eT_pl, A.aT_pl});
        }
        gsync(A.slots, A.flag, ++ep);
        // 5. logits = (kh @ mem^T) * invn  [512 x 1024, K=512]  (128 tiles 64x64, BK=64 -> 8 iters)
        if (bid < 128) {
            int g = bid & 7, idx = bid >> 3;           // idx 0..15
            int bx = g * 2 + (idx & 1), by = idx >> 1; // bx 0..15, by 0..7
            dev_logits(sm, bx, by, A);
        }
        gsync(A.slots, A.flag, ++ep);
        // 6. addressing tail -> ww/wr masters + planes  (512 rows, 1 per block)
        for (int row = bid; row < 2 * B_; row += NB_) dev_addr(sm, row, A);
        gsync(A.slots, A.flag, ++ep);
    }
}

// ---------------- generic 3-product MFMA GEMM (prologue use only) ----------------
template <int TM, class Epi>
__global__ __launch_bounds__(256) void gemm2(const u16* __restrict__ Ap, int lda, int apl,
                                             const u16* __restrict__ Bp, int ldb, int bpl,
                                             int K, Epi epi) {
    constexpr int AL = (TM * 32 * 2) / (256 * 8);
    constexpr int MT = TM / 32;
    __shared__ u16 As[2][TM][40];
    __shared__ u16 Bs[2][64][40];
    const int tid = threadIdx.x, lane = tid & 63, w = tid >> 6;
    const int wy = w >> 1, wx = w & 1, q = lane >> 4, l15 = lane & 15;
    const int row0 = blockIdx.y * TM, col0 = blockIdx.x * 64;
    uint4 ra[AL], rb[2];
    auto loadA = [&](int k0) {
#pragma unroll
        for (int j = 0; j < AL; j++) {
            int s = j * 256 + tid, p = s / (TM * 4), rr = (s >> 2) % TM, kg = s & 3;
            ra[j] = *(const uint4*)(Ap + (size_t)p * apl + (size_t)(row0 + rr) * lda + k0 + kg * 8);
        }
    };
    auto loadB = [&](int k0) {
#pragma unroll
        for (int j = 0; j < 2; j++) {
            int s = j * 256 + tid, p = s >> 8, rr = (s >> 2) & 63, kg = s & 3;
            rb[j] = *(const uint4*)(Bp + (size_t)p * bpl + (size_t)(col0 + rr) * ldb + k0 + kg * 8);
        }
    };
    v4f acc[MT][2] = {};
    loadA(0); loadB(0);
    for (int k0 = 0; k0 < K; k0 += 32) {
#pragma unroll
        for (int j = 0; j < AL; j++) {
            int s = j * 256 + tid, p = s / (TM * 4), rr = (s >> 2) % TM, kg = s & 3;
            *(uint4*)&As[p][rr][kg * 8] = ra[j];
        }
#pragma unroll
        for (int j = 0; j < 2; j++) {
            int s = j * 256 + tid, p = s >> 8, rr = (s >> 2) & 63, kg = s & 3;
            *(uint4*)&Bs[p][rr][kg * 8] = rb[j];
        }
        __syncthreads();
        if (k0 + 32 < K) { loadA(k0 + 32); loadB(k0 + 32); }
        v8s af[MT][2], bf[2][2];
#pragma unroll
        for (int mt = 0; mt < MT; mt++) {
            af[mt][0] = *(const v8s*)&As[0][wy * (TM / 2) + mt * 16 + l15][q * 8];
            af[mt][1] = *(const v8s*)&As[1][wy * (TM / 2) + mt * 16 + l15][q * 8];
        }
#pragma unroll
        for (int nt = 0; nt < 2; nt++) {
            bf[nt][0] = *(const v8s*)&Bs[0][wx * 32 + nt * 16 + l15][q * 8];
            bf[nt][1] = *(const v8s*)&Bs[1][wx * 32 + nt * 16 + l15][q * 8];
        }
#pragma unroll
        for (int mt = 0; mt < MT; mt++)
#pragma unroll
            for (int nt = 0; nt < 2; nt++) {
                v4f c = acc[mt][nt];
                c = MFMA(af[mt][0], bf[nt][0], c);
                c = MFMA(af[mt][0], bf[nt][1], c);
                c = MFMA(af[mt][1], bf[nt][0], c);
                acc[mt][nt] = c;
            }
        __syncthreads();
    }
#pragma unroll
    for (int mt = 0; mt < MT; mt++)
#pragma unroll
        for (int nt = 0; nt < 2; nt++)
            epi(row0 + wy * (TM / 2) + mt * 16 + q * 4, col0 + wx * 32 + nt * 16 + l15, acc[mt][nt]);
}

// ---------------- xwx GEMM: rows (t*256+b), A split from f32 on the fly, out -> d_out[b][t][:] ----------------
__global__ __launch_bounds__(256) void gemm2_xwx(const float* __restrict__ x, const u16* __restrict__ WxT,
                                                 float* __restrict__ outbuf) {
    __shared__ u16 As[2][64][40];
    __shared__ u16 Bs[2][64][40];
    const int tid = threadIdx.x, lane = tid & 63, w = tid >> 6;
    const int wy = w >> 1, wx = w & 1, q = lane >> 4, l15 = lane & 15;
    const int row0 = blockIdx.y * 64, col0 = blockIdx.x * 64;
    const int sr = tid >> 2, ss = (tid & 3) * 8;
    const int arow = row0 + sr, ab = arow & 255, at = arow >> 8;
    const float* Asrc = x + ((size_t)ab * T_ + at) * I_ + ss;
    v4f acc[2][2] = {};
    for (int k0 = 0; k0 < I_; k0 += 32) {
        float4 f0 = *(const float4*)(Asrc + k0);
        float4 f1 = *(const float4*)(Asrc + k0 + 4);
        float av8[8] = {f0.x, f0.y, f0.z, f0.w, f1.x, f1.y, f1.z, f1.w};
#pragma unroll
        for (int j = 0; j < 8; j++) {
            u16 h, m; split2(av8[j], h, m);
            As[0][sr][ss + j] = h; As[1][sr][ss + j] = m;
        }
#pragma unroll
        for (int p = 0; p < 2; p++)
            *(uint4*)&Bs[p][sr][ss] = *(const uint4*)&WxT[(size_t)p * PL_WXT + (size_t)(col0 + sr) * I_ + k0 + ss];
        __syncthreads();
        v8s af[2][2], bf[2][2];
#pragma unroll
        for (int mt = 0; mt < 2; mt++) {
            af[mt][0] = *(const v8s*)&As[0][wy * 32 + mt * 16 + l15][q * 8];
            af[mt][1] = *(const v8s*)&As[1][wy * 32 + mt * 16 + l15][q * 8];
            bf[mt][0] = *(const v8s*)&Bs[0][wx * 32 + mt * 16 + l15][q * 8];
            bf[mt][1] = *(const v8s*)&Bs[1][wx * 32 + mt * 16 + l15][q * 8];
        }
#pragma unroll
        for (int mt = 0; mt < 2; mt++)
#pragma unroll
            for (int nt = 0; nt < 2; nt++) {
                v4f c = acc[mt][nt];
                c = MFMA(af[mt][0], bf[nt][0], c);
                c = MFMA(af[mt][0], bf[nt][1], c);
                c = MFMA(af[mt][1], bf[nt][0], c);
                acc[mt][nt] = c;
            }
        __syncthreads();
    }
#pragma unroll
    for (int mt = 0; mt < 2; mt++)
#pragma unroll
        for (int nt = 0; nt < 2; nt++) {
            int r0 = row0 + wy * 32 + mt * 16 + q * 4;
            int c  = col0 + wx * 32 + nt * 16 + l15;
#pragma unroll
            for (int r = 0; r < 4; r++) {
                int row = r0 + r, b = row & 255, t = row >> 8;
                outbuf[((size_t)b * T_ + t) * O_ + c] = acc[mt][nt][r];
            }
        }
}

// ---------------- decomp: transpose + split2: in f32 [R][ldin] cols c0.. -> planes [C][R] ----------------
__global__ __launch_bounds__(256) void decomp_t(const float* __restrict__ in, int ldin, int c0,
                                                int R, u16* __restrict__ outp, int opl) {
    __shared__ float Ls[32][33];
    const int r0 = blockIdx.x * 32, cB = blockIdx.y * 32;
    const int tid = threadIdx.x;
    int lr = tid >> 3, lc = (tid & 7) * 4;
#pragma unroll
    for (int j = 0; j < 4; j++)
        Ls[lr][lc + j] = in[(size_t)(r0 + lr) * ldin + c0 + cB + lc + j];
    __syncthreads();
    int lc2 = tid >> 3, lr2 = (tid & 7) * 4;
    u16 hv[4], mv[4];
#pragma unroll
    for (int j = 0; j < 4; j++) split2(Ls[lr2 + j][lc2], hv[j], mv[j]);
    size_t base = (size_t)(cB + lc2) * R + r0 + lr2;
    *(ushort4*)&outp[0 * (size_t)opl + base] = make_ushort4(hv[0], hv[1], hv[2], hv[3]);
    *(ushort4*)&outp[1 * (size_t)opl + base] = make_ushort4(mv[0], mv[1], mv[2], mv[3]);
}

// ---------------- init / misc ----------------
__global__ __launch_bounds__(512) void wh6_kernel(const float* __restrict__ Whw, const float* __restrict__ Whr,
                                                  float* __restrict__ w6w, float* __restrict__ w6r,
                                                  unsigned* __restrict__ barz) {
    int k = threadIdx.x;
    if (blockIdx.x == 0) {
        for (int i = k; i < NB_ * 16 + 16; i += 512) barz[i] = 0u;  // 512 slots*16 + flag line
    }
    const float* src = blockIdx.x ? Whr : Whw;
    float* dst = blockIdx.x ? w6r : w6w;
#pragma unroll
    for (int j = 0; j < 6; j++) dst[k * 6 + j] = src[(size_t)k * (M_ + 6) + M_ + j];
}
__global__ __launch_bounds__(256) void init_mem(const float* __restrict__ mem0, float* __restrict__ memf,
                                                u16* __restrict__ mem_pl, u16* __restrict__ memT_pl) {
    int n = blockIdx.x;
    for (int c = threadIdx.x; c < M_; c += 256) {
        float v = mem0[(size_t)n * M_ + c];
        size_t idx = (size_t)n * M_ + c;
        memf[idx] = v;
        u16 h, m; split2(v, h, m);
        mem_pl[idx] = h; mem_pl[PL_MEM + idx] = m;
        size_t tb = (size_t)c * N_ + n;
        memT_pl[tb] = h; memT_pl[PL_MEM + tb] = m;
    }
}
__global__ __launch_bounds__(256) void init_w(const float* __restrict__ wr0, const float* __restrict__ ww0,
                                              float* __restrict__ wrf, float* __restrict__ wwf,
                                              u16* __restrict__ wr_pl, u16* __restrict__ wwT_pl) {
    int b = blockIdx.x;
    for (int n = threadIdx.x; n < N_; n += 256) {
        size_t idx = (size_t)b * N_ + n;
        float vw = ww0[idx]; wwf[idx] = vw;
        u16 h, m; split2(vw, h, m);
        size_t tb = (size_t)n * B_ + b;
        wwT_pl[tb] = h; wwT_pl[PL_W + tb] = m;
        float vr = wr0[idx]; wrf[idx] = vr;
        split2(vr, h, m);
        wr_pl[idx] = h; wr_pl[PL_W + idx] = m;
    }
}
__global__ __launch_bounds__(64) void init_h(const float* __restrict__ h0, float* __restrict__ hf,
                                             u16* __restrict__ hp) {
    int b = blockIdx.x;
    for (int c = threadIdx.x; c < H_; c += 64) {
        size_t idx = (size_t)b * H_ + c;
        float v = h0[idx];
        hf[idx] = v;
        u16 h, m; split2(v, h, m);
        hp[idx] = h; hp[PL_H + idx] = m;
    }
}

// ---------------- host ----------------
extern "C" void kernel_launch(void* const* d_in, const int* in_sizes, int n_in,
                              void* d_out, int out_size, void* d_ws, size_t ws_size,
                              hipStream_t stream) {
    (void)in_sizes; (void)n_in; (void)out_size; (void)ws_size;
    const float* x    = (const float*)d_in[0];
    const float* mem0 = (const float*)d_in[1];
    const float* wr0  = (const float*)d_in[2];
    const float* ww0  = (const float*)d_in[3];
    const float* h0   = (const float*)d_in[4];
    const float* Wx   = (const float*)d_in[5];
    const float* Wr   = (const float*)d_in[6];
    const float* bh   = (const float*)d_in[7];
    const float* Whr  = (const float*)d_in[8];
    const float* bhr  = (const float*)d_in[9];
    const float* Whw  = (const float*)d_in[10];
    const float* bhw  = (const float*)d_in[11];
    const float* Wea  = (const float*)d_in[12];
    const float* bea  = (const float*)d_in[13];
    const float* Wo   = (const float*)d_in[14];
    const float* bo   = (const float*)d_in[15];
    float* out = (float*)d_out;

    char* wsb = (char*)d_ws;
    size_t off = 0;
    auto carveU = [&](size_t elems) { u16* p = (u16*)(wsb + off); off += elems * sizeof(u16); return p; };
    u16* BigT    = carveU(2 * (size_t)PL_BIG);
    u16* WxT     = carveU(2 * (size_t)PL_WXT);
    u16* WrT     = carveU(2 * (size_t)PL_WRT);
    u16* mem_pl  = carveU(2 * (size_t)PL_MEM);
    u16* memT_pl = carveU(2 * (size_t)PL_MEM);
    u16* wwT_pl  = carveU(2 * (size_t)PL_W);
    u16* wr_pl   = carveU(2 * (size_t)PL_W);
    u16* h_pl    = carveU(2 * (size_t)PL_H);
    u16* r_pl    = carveU(2 * (size_t)PL_H);
    u16* eT_pl   = carveU(2 * (size_t)PL_H);
    u16* aT_pl   = carveU(2 * (size_t)PL_H);
    u16* kh_pl   = carveU(2 * (size_t)PL_KH);
    auto carveF = [&](size_t elems) { float* p = (float*)(wsb + off); off += elems * sizeof(float); return p; };
    float* memf   = carveF((size_t)N_ * M_);
    float* wwf    = carveF((size_t)B_ * N_);
    float* wrf    = carveF((size_t)B_ * N_);
    float* hf     = carveF((size_t)B_ * H_);
    float* logits = carveF((size_t)2 * B_ * N_);
    float* ssqp   = carveF((size_t)N_ * 8);
    float* w6w    = carveF(H_ * 6);
    float* w6r    = carveF(H_ * 6);
    // barrier region: NB_ slots (64B apart) + flag on its own line
    off = (off + 127) & ~(size_t)127;
    unsigned* slots = (unsigned*)(wsb + off);           // slots[NB_*16]
    unsigned* flag  = slots + NB_ * 16;                 // 64B-aligned
    off += (NB_ * 16 + 16) * sizeof(unsigned) + 64;

    // ---- prologue: weight decomposition + state init (also zeroes the barrier region) ----
    decomp_t<<<dim3(16, 16), 256, 0, stream>>>(Whw, M_ + 6, 0, 512, BigT, PL_BIG);                       // rows 0-511
    decomp_t<<<dim3(16, 16), 256, 0, stream>>>(Whr, M_ + 6, 0, 512, BigT + (size_t)512 * 512, PL_BIG);   // rows 512-1023
    decomp_t<<<dim3(16, 16), 256, 0, stream>>>(Wo, 512, 0, 512, BigT + (size_t)1024 * 512, PL_BIG);      // rows 1024-1535
    decomp_t<<<dim3(16, 32), 256, 0, stream>>>(Wea, 1024, 0, 512, BigT + (size_t)1536 * 512, PL_BIG);    // rows 1536-2559
    decomp_t<<<dim3(16, 16), 256, 0, stream>>>(Wx, 512, 0, 512, WxT, PL_WXT);
    decomp_t<<<dim3(16, 16), 256, 0, stream>>>(Wr, 512, 0, 512, WrT, PL_WRT);
    wh6_kernel<<<2, 512, 0, stream>>>(Whw, Whr, w6w, w6r, slots);
    init_mem<<<N_, 256, 0, stream>>>(mem0, memf, mem_pl, memT_pl);
    init_w<<<B_, 256, 0, stream>>>(wr0, ww0, wrf, wwf, wr_pl, wwT_pl);
    init_h<<<B_, 64, 0, stream>>>(h0, hf, h_pl);
    // xwx for all (t,b) -> stored in d_out slots [b][t][:]
    gemm2_xwx<<<dim3(8, 512), 256, 0, stream>>>(x, WxT, out);
    // ea for step 0 from h0
    gemm2<32, EpiEA0><<<dim3(16, 8), 256, 0, stream>>>(
        h_pl, 512, PL_H, BigT + (size_t)1536 * 512, 512, PL_BIG, 512, EpiEA0{bea, eT_pl, aT_pl});

    // ---- the entire T-loop: one persistent kernel, fence-free, BK=64 for P2/P3/P5 ----
    NtmArgs A;
    A.BigT = BigT; A.WxT = WxT; A.WrT = WrT;
    A.mem_pl = mem_pl; A.memT_pl = memT_pl; A.wwT_pl = wwT_pl; A.wr_pl = wr_pl;
    A.h_pl = h_pl; A.r_pl = r_pl; A.eT_pl = eT_pl; A.aT_pl = aT_pl; A.kh_pl = kh_pl;
    A.memf = memf; A.wwf = wwf; A.wrf = wrf; A.hf = hf; A.logits = logits; A.ssqp = ssqp;
    A.w6w = w6w; A.w6r = w6r; A.bh = bh; A.bhw = bhw; A.bhr = bhr; A.bea = bea; A.bo = bo;
    A.out = out;
    A.slots = slots;
    A.flag = flag;
    ntm_loop<<<dim3(NB_), dim3(256), 0, stream>>>(A);
}

// Round 11
// 15986.806 us; speedup vs baseline: 1.6313x; 1.1320x over previous
//
#include <hip/hip_runtime.h>
#include <math.h>

// NTM recurrence. GEMMs via 3-product 2-plane bf16-split MFMA (~2^-17 rel err per GEMM,
// fp32 state masters). T-loop inside ONE persistent kernel (512 blocks, 2/CU co-resident).
// Coherence (r4/r7 scheme): NO cache fences. Mutable cross-block data via agent-scope sc1
// accesses; read-only weights normal-cached (L2-resident forever). The sc1 path is
// REQUEST-throughput-bound (r9 falsified iteration-count; r4->r7 confirmed request-count).
// r11 = r7 + hi/lo planes INTERLEAVED as one u32 per element: every plane store becomes
// 1x4B instead of 2x2B (~3M -> 1.7M store reqs/step). Loads stay compiler-tracked
// __hip_atomic_load<u64> pairs (r10's asm dwordx4 loads caused spill-before-wait NaNs).
// Structure (phases/tiles/swizzles/barrier) byte-identical to r7 (best passing: 17.16ms).
// B=256 T=128 I=512 H=512 N=1024 M=512 O=512
#define B_ 256
#define T_ 128
#define I_ 512
#define H_ 512
#define N_ 1024
#define M_ 512
#define O_ 512
#define EPS_ 1e-8f
#define NB_ 512  // persistent grid: 512 blocks x 256 thr, 2 blocks/CU co-resident

typedef unsigned short u16;
typedef unsigned u32;
typedef unsigned long long u64;
typedef __attribute__((ext_vector_type(8))) short v8s;   // 8 bf16 = 4 VGPRs
typedef __attribute__((ext_vector_type(4))) float v4f;   // MFMA acc

#define MFMA(a, b, c) __builtin_amdgcn_mfma_f32_16x16x32_bf16(a, b, c, 0, 0, 0)

// ---------------- sc1 (agent-coherent) access helpers ----------------
template <typename T>
__device__ __forceinline__ T lda_(const T* p) {
    return __hip_atomic_load(const_cast<T*>(p), __ATOMIC_RELAXED, __HIP_MEMORY_SCOPE_AGENT);
}
template <typename T>
__device__ __forceinline__ void sta_(T* p, T v) {
    __hip_atomic_store(p, v, __ATOMIC_RELAXED, __HIP_MEMORY_SCOPE_AGENT);
}
__device__ __forceinline__ uint4 ld16_(const u32* p) {  // 16B as 2 x 8B sc1 (compiler-tracked)
    u64 lo = lda_((const u64*)p);
    u64 hi = lda_((const u64*)p + 1);
    uint4 r;
    r.x = (u32)lo; r.y = (u32)(lo >> 32);
    r.z = (u32)hi; r.w = (u32)(hi >> 32);
    return r;
}

// ---------------- scalar helpers ----------------
__device__ __forceinline__ float sigm_(float x) { return 1.f / (1.f + expf(-x)); }
__device__ __forceinline__ float softplus_(float x) { return x > 20.f ? x : log1pf(expf(x)); }
__device__ __forceinline__ u16 f2bf(float f) {
    unsigned u = __float_as_uint(f);
    u += 0x7fffu + ((u >> 16) & 1u);
    return (u16)(u >> 16);
}
__device__ __forceinline__ float bf2f(u16 h) { return __uint_as_float((unsigned)h << 16); }
__device__ __forceinline__ void split2(float f, u16& h, u16& m) {
    h = f2bf(f);
    m = f2bf(f - bf2f(h));
}
__device__ __forceinline__ u32 pack2_(float f) {  // interleaved plane value: hi | lo<<16
    u16 h, m; split2(f, h, m);
    return (u32)h | ((u32)m << 16);
}
// de-interleave 4 packed elems (16B) -> two 8B words per plane
__device__ __forceinline__ void deint_(uint4 r, u32* hi, u32* lo) {
    hi[0] = (r.x & 0xffffu) | (r.y << 16);
    hi[1] = (r.z & 0xffffu) | (r.w << 16);
    lo[0] = (r.x >> 16) | (r.y & 0xffff0000u);
    lo[1] = (r.z >> 16) | (r.w & 0xffff0000u);
}

__device__ __forceinline__ float wave_sum_(float v) {
#pragma unroll
    for (int o = 32; o > 0; o >>= 1) v += __shfl_down(v, o);
    return v;
}
__device__ __forceinline__ float wave_max_(float v) {
#pragma unroll
    for (int o = 32; o > 0; o >>= 1) v = fmaxf(v, __shfl_down(v, o));
    return v;
}
__device__ float block_sum_(float v, float* s) {
    int lane = threadIdx.x & 63, wid = threadIdx.x >> 6, nw = blockDim.x >> 6;
    v = wave_sum_(v);
    if (lane == 0) s[wid] = v;
    __syncthreads();
    float r = (threadIdx.x < nw) ? s[threadIdx.x] : 0.f;
    if (wid == 0) { r = wave_sum_(r); if (lane == 0) s[0] = r; }
    __syncthreads();
    float out = s[0];
    __syncthreads();
    return out;
}
__device__ float block_max_(float v, float* s) {
    int lane = threadIdx.x & 63, wid = threadIdx.x >> 6, nw = blockDim.x >> 6;
    v = wave_max_(v);
    if (lane == 0) s[wid] = v;
    __syncthreads();
    float r = (threadIdx.x < nw) ? s[threadIdx.x] : -3.4e38f;
    if (wid == 0) { r = wave_max_(r); if (lane == 0) s[0] = r; }
    __syncthreads();
    float out = s[0];
    __syncthreads();
    return out;
}

// ---------------- grid barrier: per-block slots + release flag, NO fences ----------------
__device__ __forceinline__ void gsync(unsigned* slots, unsigned* flag, unsigned epoch) {
    __syncthreads();
    if (threadIdx.x == 0)
        __hip_atomic_store(&slots[blockIdx.x * 16], epoch, __ATOMIC_RELAXED,
                           __HIP_MEMORY_SCOPE_AGENT);
    if (blockIdx.x == 0) {
        while (__hip_atomic_load(&slots[threadIdx.x * 16], __ATOMIC_RELAXED,
                                 __HIP_MEMORY_SCOPE_AGENT) < epoch)
            __builtin_amdgcn_s_sleep(1);
        while (__hip_atomic_load(&slots[(threadIdx.x + 256) * 16], __ATOMIC_RELAXED,
                                 __HIP_MEMORY_SCOPE_AGENT) < epoch)
            __builtin_amdgcn_s_sleep(1);
        __syncthreads();  // all 512 slots arrived
        if (threadIdx.x == 0)
            __hip_atomic_store(flag, epoch, __ATOMIC_RELAXED, __HIP_MEMORY_SCOPE_AGENT);
    } else if (threadIdx.x == 0) {
        while (__hip_atomic_load(flag, __ATOMIC_RELAXED, __HIP_MEMORY_SCOPE_AGENT) < epoch)
            __builtin_amdgcn_s_sleep(1);
    }
    __syncthreads();
}

// ---------------- epilogues (per 16x16 fragment: rows r0..r0+3 (A-rows), col c (B-row)) ----------------
struct EpiEA0 {  // prologue ea only (separate kernel launch -> plain stores OK): r=b, c=m
    const float* bea; u32* eT; u32* aT;
    __device__ void operator()(int r0, int c, v4f v) const {
#pragma unroll
        for (int r = 0; r < 4; r++) {
            float val = v[r] + bea[c];
            u32* dst;
            int b = r0 + r;
            if (c < M_) { val = sigm_(val); dst = eT + (size_t)c * B_ + b; }
            else        { val = tanhf(val); dst = aT + (size_t)(c - M_) * B_ + b; }
            dst[0] = pack2_(val);
        }
    }
};
struct EpiR {  // C[b][m] -> r interleaved (sc1)
    u32* rp;
    __device__ void operator()(int r0, int c, v4f v) const {
#pragma unroll
        for (int r = 0; r < 4; r++)
            sta_(rp + (size_t)(r0 + r) * M_ + c, pack2_(v[r]));
    }
};
struct EpiH {  // C[b][hdim] + xwx(in d_out layout, cached read) + bh -> tanh -> h_i (sc1)
    const float* xwxt; const float* bh; u32* hp;
    __device__ void operator()(int r0, int c, v4f v) const {
#pragma unroll
        for (int r = 0; r < 4; r++) {
            int b = r0 + r;
            float val = tanhf(v[r] + xwxt[(size_t)b * (T_ * O_) + c] + bh[c]);
            sta_(hp + (size_t)b * H_ + c, pack2_(val));
        }
    }
};
struct EpiFused {  // c<1024: keys; 1024..1535: out; 1536..: ea(next step)
    const float* bhw; const float* bhr; const float* bo; const float* bea;
    u32* khp; float* outt; u32* eT; u32* aT;
    __device__ void operator()(int r0, int c, v4f v) const {
        if (c < 1024) {
            int head = c >> 9, key = c & 511;
            const float* bb = head ? bhr : bhw;
#pragma unroll
            for (int r = 0; r < 4; r++) {
                float val = tanhf(v[r] + bb[key]);
                sta_(khp + (size_t)(head * 256 + r0 + r) * M_ + key, pack2_(val));
            }
        } else if (c < 1536) {
            int o = c - 1024;
#pragma unroll
            for (int r = 0; r < 4; r++)
                outt[(size_t)(r0 + r) * (T_ * O_) + o] = sigm_(v[r] + bo[o]);  // host-read only
        } else {
            int m = c - 1536;
#pragma unroll
            for (int r = 0; r < 4; r++) {
                float val = v[r] + bea[m];
                u32* dst;
                int b = r0 + r;
                if (m < M_) { val = sigm_(val); dst = eT + (size_t)m * B_ + b; }
                else        { val = tanhf(val); dst = aT + (size_t)(m - M_) * B_ + b; }
                sta_(dst, pack2_(val));
            }
        }
    }
};

// ---------------- persistent-kernel args ----------------
struct NtmArgs {
    const u32 *BigT, *WrT;
    u32 *mem_i, *memT_i, *wwT_i, *wr_i, *h_i, *r_i, *eT_i, *aT_i, *kh_i;
    float *memf, *wwf, *wrf, *logits, *ssqp;
    const float *w6w, *w6r, *bh, *bhw, *bhr, *bea, *bo;
    float* out;
    unsigned* slots;
    unsigned* flag;
};

// ---------------- device: 3-product MFMA GEMM tile 32x64, BK=32, interleaved operands ----------------
// AS/BS: operand via sc1 8B loads (mutable) vs normal cached (read-only weight).
template <bool AS, bool BS, class Epi>
__device__ __forceinline__ void dev_gemm32(char* smc, const u32* __restrict__ Ap, int lda,
                                           const u32* __restrict__ Bp, int ldb,
                                           int K, int row0, int col0, const Epi& epi) {
    typedef u16 (*T40A)[32][40];
    typedef u16 (*T40B)[64][40];
    T40A As = (T40A)smc;            // [2][32][40] = 5120 B
    T40B Bs = (T40B)(smc + 5120);   // [2][64][40] = 10240 B
    const int tid = threadIdx.x, lane = tid & 63, w = tid >> 6;
    const int wy = w >> 1, wx = w & 1, q = lane >> 4, l15 = lane & 15;
    uint4 ra, rb[2];
    auto loadA = [&](int k0) {
        int row = tid >> 3, c4 = (tid & 7) * 4;
        const u32* ap = Ap + (size_t)(row0 + row) * lda + k0 + c4;
        ra = AS ? ld16_(ap) : *(const uint4*)ap;
    };
    auto loadB = [&](int k0) {
#pragma unroll
        for (int j = 0; j < 2; j++) {
            int s = j * 256 + tid, row = s >> 3, c4 = (s & 7) * 4;
            const u32* bp = Bp + (size_t)(col0 + row) * ldb + k0 + c4;
            rb[j] = BS ? ld16_(bp) : *(const uint4*)bp;
        }
    };
    v4f acc[2] = {};
    loadA(0); loadB(0);
    for (int k0 = 0; k0 < K; k0 += 32) {
        {
            int row = tid >> 3, c4 = (tid & 7) * 4;
            u32 hi[2], lo[2]; deint_(ra, hi, lo);
            *(uint2*)&As[0][row][c4] = make_uint2(hi[0], hi[1]);
            *(uint2*)&As[1][row][c4] = make_uint2(lo[0], lo[1]);
        }
#pragma unroll
        for (int j = 0; j < 2; j++) {
            int s = j * 256 + tid, row = s >> 3, c4 = (s & 7) * 4;
            u32 hi[2], lo[2]; deint_(rb[j], hi, lo);
            *(uint2*)&Bs[0][row][c4] = make_uint2(hi[0], hi[1]);
            *(uint2*)&Bs[1][row][c4] = make_uint2(lo[0], lo[1]);
        }
        __syncthreads();
        if (k0 + 32 < K) { loadA(k0 + 32); loadB(k0 + 32); }
        v8s af0 = *(const v8s*)&As[0][wy * 16 + l15][q * 8];
        v8s af1 = *(const v8s*)&As[1][wy * 16 + l15][q * 8];
        v8s bf[2][2];
#pragma unroll
        for (int nt = 0; nt < 2; nt++) {
            bf[nt][0] = *(const v8s*)&Bs[0][wx * 32 + nt * 16 + l15][q * 8];
            bf[nt][1] = *(const v8s*)&Bs[1][wx * 32 + nt * 16 + l15][q * 8];
        }
#pragma unroll
        for (int nt = 0; nt < 2; nt++) {
            v4f c = acc[nt];
            c = MFMA(af0, bf[nt][0], c);
            c = MFMA(af0, bf[nt][1], c);
            c = MFMA(af1, bf[nt][0], c);
            acc[nt] = c;
        }
        __syncthreads();
    }
#pragma unroll
    for (int nt = 0; nt < 2; nt++)
        epi(row0 + wy * 16 + q * 4, col0 + wx * 32 + nt * 16 + l15, acc[nt]);
}

// ---------------- device: 3-product MFMA GEMM tile 64x64, BK=32, interleaved ----------------
template <bool AS, bool BS, class Epi>
__device__ __forceinline__ void dev_gemm64(char* smc, const u32* __restrict__ Ap, int lda,
                                           const u32* __restrict__ Bp, int ldb,
                                           int K, int row0, int col0, const Epi& epi) {
    typedef u16 (*T64)[64][40];
    T64 As = (T64)smc;            // 10240 B
    T64 Bs = (T64)(smc + 10240);  // 10240 B
    const int tid = threadIdx.x, lane = tid & 63, w = tid >> 6;
    const int wy = w >> 1, wx = w & 1, q = lane >> 4, l15 = lane & 15;
    uint4 ra[2], rb[2];
    auto loadAll = [&](int k0) {
#pragma unroll
        for (int j = 0; j < 2; j++) {
            int s = j * 256 + tid, row = s >> 3, c4 = (s & 7) * 4;
            const u32* ap = Ap + (size_t)(row0 + row) * lda + k0 + c4;
            const u32* bp = Bp + (size_t)(col0 + row) * ldb + k0 + c4;
            ra[j] = AS ? ld16_(ap) : *(const uint4*)ap;
            rb[j] = BS ? ld16_(bp) : *(const uint4*)bp;
        }
    };
    v4f acc[2][2] = {};
    loadAll(0);
    for (int k0 = 0; k0 < K; k0 += 32) {
#pragma unroll
        for (int j = 0; j < 2; j++) {
            int s = j * 256 + tid, row = s >> 3, c4 = (s & 7) * 4;
            u32 hi[2], lo[2];
            deint_(ra[j], hi, lo);
            *(uint2*)&As[0][row][c4] = make_uint2(hi[0], hi[1]);
            *(uint2*)&As[1][row][c4] = make_uint2(lo[0], lo[1]);
            deint_(rb[j], hi, lo);
            *(uint2*)&Bs[0][row][c4] = make_uint2(hi[0], hi[1]);
            *(uint2*)&Bs[1][row][c4] = make_uint2(lo[0], lo[1]);
        }
        __syncthreads();
        if (k0 + 32 < K) loadAll(k0 + 32);
        v8s af[2][2], bf[2][2];
#pragma unroll
        for (int mt = 0; mt < 2; mt++) {
            af[mt][0] = *(const v8s*)&As[0][wy * 32 + mt * 16 + l15][q * 8];
            af[mt][1] = *(const v8s*)&As[1][wy * 32 + mt * 16 + l15][q * 8];
            bf[mt][0] = *(const v8s*)&Bs[0][wx * 32 + mt * 16 + l15][q * 8];
            bf[mt][1] = *(const v8s*)&Bs[1][wx * 32 + mt * 16 + l15][q * 8];
        }
#pragma unroll
        for (int mt = 0; mt < 2; mt++)
#pragma unroll
            for (int nt = 0; nt < 2; nt++) {
                v4f c = acc[mt][nt];
                c = MFMA(af[mt][0], bf[nt][0], c);
                c = MFMA(af[mt][0], bf[nt][1], c);
                c = MFMA(af[mt][1], bf[nt][0], c);
                acc[mt][nt] = c;
            }
        __syncthreads();
    }
#pragma unroll
    for (int mt = 0; mt < 2; mt++)
#pragma unroll
        for (int nt = 0; nt < 2; nt++)
            epi(row0 + wy * 32 + mt * 16 + q * 4, col0 + wx * 32 + nt * 16 + l15, acc[mt][nt]);
}

// ---------------- device: memupd (Se=wwT@eT^T, Sa=wwT@aT^T; mem update; row ssq partials) ----------------
__device__ void dev_memupd(char* smc, int bid, const NtmArgs& A) {
    typedef u16 (*T64)[64][40];
    T64 As = (T64)smc;                 // 10240 B
    T64 Be = (T64)(smc + 10240);
    T64 Ba = (T64)(smc + 20480);
    float* ssqs = (float*)(smc + 30720);
    const int tid = threadIdx.x, lane = tid & 63, w = tid >> 6;
    const int wy = w >> 1, wx = w & 1, q = lane >> 4, l15 = lane & 15;
    const int bx = bid & 7, by = bid >> 3;
    const int row0 = by * 64, col0 = bx * 64;  // row=n, col=m
    if (tid < 64) ssqs[tid] = 0.f;
    uint4 rA[2], rE[2], rB[2];
    auto loadAll = [&](int k0) {
#pragma unroll
        for (int j = 0; j < 2; j++) {
            int s = j * 256 + tid, row = s >> 3, c4 = (s & 7) * 4;
            rA[j] = ld16_(A.wwT_i + (size_t)(row0 + row) * B_ + k0 + c4);
            rE[j] = ld16_(A.eT_i + (size_t)(col0 + row) * B_ + k0 + c4);
            rB[j] = ld16_(A.aT_i + (size_t)(col0 + row) * B_ + k0 + c4);
        }
    };
    v4f ae[2][2] = {}, aa[2][2] = {};
    loadAll(0);
    for (int k0 = 0; k0 < B_; k0 += 32) {
#pragma unroll
        for (int j = 0; j < 2; j++) {
            int s = j * 256 + tid, row = s >> 3, c4 = (s & 7) * 4;
            u32 hi[2], lo[2];
            deint_(rA[j], hi, lo);
            *(uint2*)&As[0][row][c4] = make_uint2(hi[0], hi[1]);
            *(uint2*)&As[1][row][c4] = make_uint2(lo[0], lo[1]);
            deint_(rE[j], hi, lo);
            *(uint2*)&Be[0][row][c4] = make_uint2(hi[0], hi[1]);
            *(uint2*)&Be[1][row][c4] = make_uint2(lo[0], lo[1]);
            deint_(rB[j], hi, lo);
            *(uint2*)&Ba[0][row][c4] = make_uint2(hi[0], hi[1]);
            *(uint2*)&Ba[1][row][c4] = make_uint2(lo[0], lo[1]);
        }
        __syncthreads();
        if (k0 + 32 < B_) loadAll(k0 + 32);
        v8s af[2][2], be[2][2], ba[2][2];
#pragma unroll
        for (int mt = 0; mt < 2; mt++) {
            af[mt][0] = *(const v8s*)&As[0][wy * 32 + mt * 16 + l15][q * 8];
            af[mt][1] = *(const v8s*)&As[1][wy * 32 + mt * 16 + l15][q * 8];
            be[mt][0] = *(const v8s*)&Be[0][wx * 32 + mt * 16 + l15][q * 8];
            be[mt][1] = *(const v8s*)&Be[1][wx * 32 + mt * 16 + l15][q * 8];
            ba[mt][0] = *(const v8s*)&Ba[0][wx * 32 + mt * 16 + l15][q * 8];
            ba[mt][1] = *(const v8s*)&Ba[1][wx * 32 + mt * 16 + l15][q * 8];
        }
#pragma unroll
        for (int mt = 0; mt < 2; mt++)
#pragma unroll
            for (int nt = 0; nt < 2; nt++) {
                v4f c = ae[mt][nt];
                c = MFMA(af[mt][0], be[nt][0], c);
                c = MFMA(af[mt][0], be[nt][1], c);
                c = MFMA(af[mt][1], be[nt][0], c);
                ae[mt][nt] = c;
                v4f d = aa[mt][nt];
                d = MFMA(af[mt][0], ba[nt][0], d);
                d = MFMA(af[mt][0], ba[nt][1], d);
                d = MFMA(af[mt][1], ba[nt][0], d);
                aa[mt][nt] = d;
            }
        __syncthreads();
    }
    const float invB = 1.f / (float)B_;
#pragma unroll
    for (int mt = 0; mt < 2; mt++)
#pragma unroll
        for (int nt = 0; nt < 2; nt++) {
            int r0 = row0 + wy * 32 + mt * 16 + q * 4;
            int c  = col0 + wx * 32 + nt * 16 + l15;
            u32 pv4[4];
#pragma unroll
            for (int r = 0; r < 4; r++) {
                size_t idx = (size_t)(r0 + r) * M_ + c;
                float old = A.memf[idx];  // block-private tile (same block every step): cached
                float nv = old * (1.f - ae[mt][nt][r] * invB) + aa[mt][nt][r] * invB;
                A.memf[idx] = nv;
                u32 pv = pack2_(nv);
                sta_(A.mem_i + idx, pv);
                pv4[r] = pv;
                atomicAdd(&ssqs[r0 + r - row0], nv * nv);
            }
            size_t tb = (size_t)c * N_ + r0;
            sta_((u64*)(A.memT_i + tb), (u64)pv4[0] | ((u64)pv4[1] << 32));
            sta_((u64*)(A.memT_i + tb) + 1, (u64)pv4[2] | ((u64)pv4[3] << 32));
        }
    __syncthreads();
    if (tid < 64) sta_(A.ssqp + (size_t)(row0 + tid) * 8 + bx, ssqs[tid]);
}

// ---------------- device: logits = (kh @ mem^T) * invn  (64x64, BK=32, interleaved) ----------------
__device__ void dev_logits(char* smc, int bx, int by, const NtmArgs& A) {
    typedef u16 (*T64)[64][40];
    T64 As = (T64)smc;
    T64 Bs = (T64)(smc + 10240);
    float* invn_s = (float*)(smc + 20480);
    const int tid = threadIdx.x, lane = tid & 63, w = tid >> 6;
    const int wy = w >> 1, wx = w & 1, q = lane >> 4, l15 = lane & 15;
    const int row0 = by * 64, col0 = bx * 64;  // row in [0,512), col=n
    if (tid < 64) {
        float s = 0.f;
#pragma unroll
        for (int j = 0; j < 8; j++) s += lda_(A.ssqp + (size_t)(col0 + tid) * 8 + j);
        invn_s[tid] = 1.f / (sqrtf(s) + EPS_);
    }
    uint4 ra[2], rb[2];
    auto loadAll = [&](int k0) {
#pragma unroll
        for (int j = 0; j < 2; j++) {
            int s = j * 256 + tid, row = s >> 3, c4 = (s & 7) * 4;
            ra[j] = ld16_(A.kh_i + (size_t)(row0 + row) * M_ + k0 + c4);
            rb[j] = ld16_(A.mem_i + (size_t)(col0 + row) * M_ + k0 + c4);
        }
    };
    v4f acc[2][2] = {};
    loadAll(0);
    for (int k0 = 0; k0 < M_; k0 += 32) {
#pragma unroll
        for (int j = 0; j < 2; j++) {
            int s = j * 256 + tid, row = s >> 3, c4 = (s & 7) * 4;
            u32 hi[2], lo[2];
            deint_(ra[j], hi, lo);
            *(uint2*)&As[0][row][c4] = make_uint2(hi[0], hi[1]);
            *(uint2*)&As[1][row][c4] = make_uint2(lo[0], lo[1]);
            deint_(rb[j], hi, lo);
            *(uint2*)&Bs[0][row][c4] = make_uint2(hi[0], hi[1]);
            *(uint2*)&Bs[1][row][c4] = make_uint2(lo[0], lo[1]);
        }
        __syncthreads();
        if (k0 + 32 < M_) loadAll(k0 + 32);
        v8s af[2][2], bf[2][2];
#pragma unroll
        for (int mt = 0; mt < 2; mt++) {
            af[mt][0] = *(const v8s*)&As[0][wy * 32 + mt * 16 + l15][q * 8];
            af[mt][1] = *(const v8s*)&As[1][wy * 32 + mt * 16 + l15][q * 8];
            bf[mt][0] = *(const v8s*)&Bs[0][wx * 32 + mt * 16 + l15][q * 8];
            bf[mt][1] = *(const v8s*)&Bs[1][wx * 32 + mt * 16 + l15][q * 8];
        }
#pragma unroll
        for (int mt = 0; mt < 2; mt++)
#pragma unroll
            for (int nt = 0; nt < 2; nt++) {
                v4f c = acc[mt][nt];
                c = MFMA(af[mt][0], bf[nt][0], c);
                c = MFMA(af[mt][0], bf[nt][1], c);
                c = MFMA(af[mt][1], bf[nt][0], c);
                acc[mt][nt] = c;
            }
        __syncthreads();
    }
#pragma unroll
    for (int mt = 0; mt < 2; mt++)
#pragma unroll
        for (int nt = 0; nt < 2; nt++) {
            int r0 = row0 + wy * 32 + mt * 16 + q * 4;
            int c  = col0 + wx * 32 + nt * 16 + l15;
            float in_ = invn_s[c - col0];
#pragma unroll
            for (int r = 0; r < 4; r++)
                sta_(A.logits + (size_t)(r0 + r) * N_ + c, acc[mt][nt][r] * in_);
        }
}

// ---------------- device: addressing tail ----------------
__device__ void dev_addr(char* smc, int row, const NtmArgs& A) {
    float* wgs = (float*)smc;           // N_ floats = 4096 B
    float* red = (float*)(smc + 4096);  // 8 floats
    int head = row >> 8, b = row & 255;
    const float* w6 = head ? A.w6r : A.w6w;
    const float* bias = head ? A.bhr : A.bhw;
    float* wf = head ? A.wrf : A.wwf;   // master row b: exclusively owned by this block
    int tid = threadIdx.x;
    float d0 = 0, d1 = 0, d2 = 0, d3 = 0, d4 = 0, d5 = 0, ssq = 0;
#pragma unroll
    for (int j = 0; j < 2; j++) {
        int k = tid + j * 256;
        u32 hv2 = lda_(A.h_i + (size_t)b * H_ + k);
        float hv = bf2f((u16)hv2) + bf2f((u16)(hv2 >> 16));
        const float* wk = w6 + k * 6;
        d0 += hv * wk[0]; d1 += hv * wk[1]; d2 += hv * wk[2];
        d3 += hv * wk[3]; d4 += hv * wk[4]; d5 += hv * wk[5];
        u32 kv2 = lda_(A.kh_i + (size_t)row * M_ + k);
        float kv = bf2f((u16)kv2) + bf2f((u16)(kv2 >> 16));
        ssq += kv * kv;
    }
    d0 = block_sum_(d0, red); d1 = block_sum_(d1, red); d2 = block_sum_(d2, red);
    d3 = block_sum_(d3, red); d4 = block_sum_(d4, red); d5 = block_sum_(d5, red);
    ssq = block_sum_(ssq, red);
    float beta = softplus_(d0 + bias[M_]);
    float g = sigm_(d1 + bias[M_ + 1]);
    float a0 = d2 + bias[M_ + 2], a1 = d3 + bias[M_ + 3], a2 = d4 + bias[M_ + 4];
    float mx3 = fmaxf(a0, fmaxf(a1, a2));
    float e0 = expf(a0 - mx3), e1 = expf(a1 - mx3), e2 = expf(a2 - mx3);
    float es = e0 + e1 + e2;
    float s0 = e0 / es, s1 = e1 / es, s2 = e2 / es;
    float gamma = 1.f + softplus_(d5 + bias[M_ + 5]);
    float rowsc = beta / (sqrtf(ssq) + EPS_);
    const u64* lp = (const u64*)(A.logits + (size_t)row * N_ + tid * 4);
    u64 la = lda_(lp), lb = lda_(lp + 1);
    float l[4];
    l[0] = __uint_as_float((u32)la) * rowsc;
    l[1] = __uint_as_float((u32)(la >> 32)) * rowsc;
    l[2] = __uint_as_float((u32)lb) * rowsc;
    l[3] = __uint_as_float((u32)(lb >> 32)) * rowsc;
    float mx = fmaxf(fmaxf(l[0], l[1]), fmaxf(l[2], l[3]));
    mx = block_max_(mx, red);
    float ex[4], sum = 0.f;
#pragma unroll
    for (int j = 0; j < 4; j++) { ex[j] = expf(l[j] - mx); sum += ex[j]; }
    sum = block_sum_(sum, red);
    float inv = 1.f / sum;
    float wprev[4];
#pragma unroll
    for (int j = 0; j < 4; j++) wprev[j] = wf[(size_t)b * N_ + tid * 4 + j];
#pragma unroll
    for (int j = 0; j < 4; j++) wgs[tid * 4 + j] = g * ex[j] * inv + (1.f - g) * wprev[j];
    __syncthreads();
    float wp[4], psum = 0.f;
#pragma unroll
    for (int j = 0; j < 4; j++) {
        int n = tid * 4 + j;
        float wt = s0 * wgs[(n + 1) & (N_ - 1)] + s1 * wgs[n] + s2 * wgs[(n - 1) & (N_ - 1)];
        float v = expf(gamma * logf(wt));
        wp[j] = v; psum += v;
    }
    psum = block_sum_(psum, red);
    float invp = 1.f / (psum + EPS_);
#pragma unroll
    for (int j = 0; j < 4; j++) {
        int n = tid * 4 + j;
        float val = wp[j] * invp;
        wf[(size_t)b * N_ + n] = val;  // block-private master: cached
        u32 pv = pack2_(val);
        if (head == 0) sta_(A.wwT_i + (size_t)n * B_ + b, pv);
        else           sta_(A.wr_i + (size_t)b * N_ + n, pv);
    }
}

// ---------------- persistent kernel: the whole T-loop (structure = r7) ----------------
__global__ __launch_bounds__(256, 2) void ntm_loop(NtmArgs A) {
    __shared__ __align__(16) char sm[31232];
    const int bid = blockIdx.x;
    unsigned ep = 0;
    for (int t = 0; t < T_; t++) {
        // 1. mem update + row-ssq partials  [n x m, K=256]  (128 tiles 64x64)
        if (bid < 128) dev_memupd(sm, bid, A);
        gsync(A.slots, A.flag, ++ep);
        // 2. r = wr @ mem  [256 x 512, K=1024]  (32 tiles 64x64, bx=xcd: memT slice/XCD)
        if (bid < 32) {
            int bx = bid & 7, by = bid >> 3;
            dev_gemm64<true, true>(sm, A.wr_i, 1024, A.memT_i, 1024, 1024,
                                   by * 64, bx * 64, EpiR{A.r_i});
        }
        gsync(A.slots, A.flag, ++ep);
        // 3. h = tanh(xwx + r @ Wr + bh)  [256 x 512, K=512]  (32 tiles 64x64; WrT cached)
        if (bid < 32) {
            int bx = bid & 7, by = bid >> 3;
            dev_gemm64<true, false>(sm, A.r_i, 512, A.WrT, 512, 512,
                                    by * 64, bx * 64,
                                    EpiH{A.out + (size_t)t * O_, A.bh, A.h_i});
        }
        gsync(A.slots, A.flag, ++ep);
        // 4. fused: h @ [Whw_k | Whr_k | Wo | Wea]  (320 tiles 32x64; g*5 XCD swizzle)
        if (bid < 320) {
            int g = bid & 7, idx = bid >> 3;           // idx 0..39
            int bx = g * 5 + idx % 5, by = idx / 5;    // bx 0..39, by 0..7
            dev_gemm32<true, false>(sm, A.h_i, 512, A.BigT, 512, 512,
                                    by * 32, bx * 64,
                                    EpiFused{A.bhw, A.bhr, A.bo, A.bea, A.kh_i,
                                             A.out + (size_t)t * O_, A.eT_i, A.aT_i});
        }
        gsync(A.slots, A.flag, ++ep);
        // 5. logits = (kh @ mem^T) * invn  [512 x 1024, K=512]  (128 tiles; 2 mem slices/XCD)
        if (bid < 128) {
            int g = bid & 7, idx = bid >> 3;           // idx 0..15
            int bx = g * 2 + (idx & 1), by = idx >> 1; // bx 0..15, by 0..7
            dev_logits(sm, bx, by, A);
        }
        gsync(A.slots, A.flag, ++ep);
        // 6. addressing tail -> ww/wr masters + planes  (512 rows, 1 per block)
        for (int row = bid; row < 2 * B_; row += NB_) dev_addr(sm, row, A);
        gsync(A.slots, A.flag, ++ep);
    }
}

// ---------------- prologue GEMM wrapper (ea for step 0): interleaved, cached loads ----------------
__global__ __launch_bounds__(256) void gemm32_pro(const u32* __restrict__ Ap, int lda,
                                                  const u32* __restrict__ Bp, int ldb,
                                                  int K, EpiEA0 epi) {
    __shared__ __align__(16) char sm[15616];
    dev_gemm32<false, false>(sm, Ap, lda, Bp, ldb, K, blockIdx.y * 32, blockIdx.x * 64, epi);
}

// ---------------- xwx GEMM: rows (t*256+b), A split from f32 on the fly, B interleaved ----------------
__global__ __launch_bounds__(256) void gemm2_xwx(const float* __restrict__ x, const u32* __restrict__ WxT,
                                                 float* __restrict__ outbuf) {
    __shared__ u16 As[2][64][40];
    __shared__ u16 Bs[2][64][40];
    const int tid = threadIdx.x, lane = tid & 63, w = tid >> 6;
    const int wy = w >> 1, wx = w & 1, q = lane >> 4, l15 = lane & 15;
    const int row0 = blockIdx.y * 64, col0 = blockIdx.x * 64;
    const int sr = tid >> 2, ss = (tid & 3) * 8;
    const int arow = row0 + sr, ab = arow & 255, at = arow >> 8;
    const float* Asrc = x + ((size_t)ab * T_ + at) * I_ + ss;
    v4f acc[2][2] = {};
    for (int k0 = 0; k0 < I_; k0 += 32) {
        float4 f0 = *(const float4*)(Asrc + k0);
        float4 f1 = *(const float4*)(Asrc + k0 + 4);
        float av8[8] = {f0.x, f0.y, f0.z, f0.w, f1.x, f1.y, f1.z, f1.w};
#pragma unroll
        for (int j = 0; j < 8; j++) {
            u16 h, m; split2(av8[j], h, m);
            As[0][sr][ss + j] = h; As[1][sr][ss + j] = m;
        }
#pragma unroll
        for (int j = 0; j < 2; j++) {
            int s = j * 256 + tid, row = s >> 3, c4 = (s & 7) * 4;
            uint4 rB = *(const uint4*)&WxT[(size_t)(col0 + row) * I_ + k0 + c4];
            u32 hi[2], lo[2]; deint_(rB, hi, lo);
            *(uint2*)&Bs[0][row][c4] = make_uint2(hi[0], hi[1]);
            *(uint2*)&Bs[1][row][c4] = make_uint2(lo[0], lo[1]);
        }
        __syncthreads();
        v8s af[2][2], bf[2][2];
#pragma unroll
        for (int mt = 0; mt < 2; mt++) {
            af[mt][0] = *(const v8s*)&As[0][wy * 32 + mt * 16 + l15][q * 8];
            af[mt][1] = *(const v8s*)&As[1][wy * 32 + mt * 16 + l15][q * 8];
            bf[mt][0] = *(const v8s*)&Bs[0][wx * 32 + mt * 16 + l15][q * 8];
            bf[mt][1] = *(const v8s*)&Bs[1][wx * 32 + mt * 16 + l15][q * 8];
        }
#pragma unroll
        for (int mt = 0; mt < 2; mt++)
#pragma unroll
            for (int nt = 0; nt < 2; nt++) {
                v4f c = acc[mt][nt];
                c = MFMA(af[mt][0], bf[nt][0], c);
                c = MFMA(af[mt][0], bf[nt][1], c);
                c = MFMA(af[mt][1], bf[nt][0], c);
                acc[mt][nt] = c;
            }
        __syncthreads();
    }
#pragma unroll
    for (int mt = 0; mt < 2; mt++)
#pragma unroll
        for (int nt = 0; nt < 2; nt++) {
            int r0 = row0 + wy * 32 + mt * 16 + q * 4;
            int c  = col0 + wx * 32 + nt * 16 + l15;
#pragma unroll
            for (int r = 0; r < 4; r++) {
                int row = r0 + r, b = row & 255, t = row >> 8;
                outbuf[((size_t)b * T_ + t) * O_ + c] = acc[mt][nt][r];
            }
        }
}

// ---------------- decomp: transpose + pack: f32 [R][ldin] cols c0.. -> interleaved [C][R] ----------------
__global__ __launch_bounds__(256) void decomp_t(const float* __restrict__ in, int ldin, int c0,
                                                int R, u32* __restrict__ outp) {
    __shared__ float Ls[32][33];
    const int r0 = blockIdx.x * 32, cB = blockIdx.y * 32;
    const int tid = threadIdx.x;
    int lr = tid >> 3, lc = (tid & 7) * 4;
#pragma unroll
    for (int j = 0; j < 4; j++)
        Ls[lr][lc + j] = in[(size_t)(r0 + lr) * ldin + c0 + cB + lc + j];
    __syncthreads();
    int lc2 = tid >> 3, lr2 = (tid & 7) * 4;
    u32 pv[4];
#pragma unroll
    for (int j = 0; j < 4; j++) pv[j] = pack2_(Ls[lr2 + j][lc2]);
    size_t base = (size_t)(cB + lc2) * R + r0 + lr2;
    *(uint4*)&outp[base] = make_uint4(pv[0], pv[1], pv[2], pv[3]);
}

// ---------------- init / misc ----------------
__global__ __launch_bounds__(512) void wh6_kernel(const float* __restrict__ Whw, const float* __restrict__ Whr,
                                                  float* __restrict__ w6w, float* __restrict__ w6r,
                                                  unsigned* __restrict__ barz) {
    int k = threadIdx.x;
    if (blockIdx.x == 0) {
        for (int i = k; i < NB_ * 16 + 16; i += 512) barz[i] = 0u;  // 512 slots*16 + flag line
    }
    const float* src = blockIdx.x ? Whr : Whw;
    float* dst = blockIdx.x ? w6r : w6w;
#pragma unroll
    for (int j = 0; j < 6; j++) dst[k * 6 + j] = src[(size_t)k * (M_ + 6) + M_ + j];
}
__global__ __launch_bounds__(256) void init_mem(const float* __restrict__ mem0, float* __restrict__ memf,
                                                u32* __restrict__ mem_i, u32* __restrict__ memT_i) {
    int n = blockIdx.x;
    for (int c = threadIdx.x; c < M_; c += 256) {
        float v = mem0[(size_t)n * M_ + c];
        size_t idx = (size_t)n * M_ + c;
        memf[idx] = v;
        u32 pv = pack2_(v);
        mem_i[idx] = pv;
        memT_i[(size_t)c * N_ + n] = pv;
    }
}
__global__ __launch_bounds__(256) void init_w(const float* __restrict__ wr0, const float* __restrict__ ww0,
                                              float* __restrict__ wrf, float* __restrict__ wwf,
                                              u32* __restrict__ wr_i, u32* __restrict__ wwT_i) {
    int b = blockIdx.x;
    for (int n = threadIdx.x; n < N_; n += 256) {
        size_t idx = (size_t)b * N_ + n;
        float vw = ww0[idx]; wwf[idx] = vw;
        wwT_i[(size_t)n * B_ + b] = pack2_(vw);
        float vr = wr0[idx]; wrf[idx] = vr;
        wr_i[idx] = pack2_(vr);
    }
}
__global__ __launch_bounds__(64) void init_h(const float* __restrict__ h0, u32* __restrict__ h_i) {
    int b = blockIdx.x;
    for (int c = threadIdx.x; c < H_; c += 64)
        h_i[(size_t)b * H_ + c] = pack2_(h0[(size_t)b * H_ + c]);
}

// ---------------- host ----------------
extern "C" void kernel_launch(void* const* d_in, const int* in_sizes, int n_in,
                              void* d_out, int out_size, void* d_ws, size_t ws_size,
                              hipStream_t stream) {
    (void)in_sizes; (void)n_in; (void)out_size; (void)ws_size;
    const float* x    = (const float*)d_in[0];
    const float* mem0 = (const float*)d_in[1];
    const float* wr0  = (const float*)d_in[2];
    const float* ww0  = (const float*)d_in[3];
    const float* h0   = (const float*)d_in[4];
    const float* Wx   = (const float*)d_in[5];
    const float* Wr   = (const float*)d_in[6];
    const float* bh   = (const float*)d_in[7];
    const float* Whr  = (const float*)d_in[8];
    const float* bhr  = (const float*)d_in[9];
    const float* Whw  = (const float*)d_in[10];
    const float* bhw  = (const float*)d_in[11];
    const float* Wea  = (const float*)d_in[12];
    const float* bea  = (const float*)d_in[13];
    const float* Wo   = (const float*)d_in[14];
    const float* bo   = (const float*)d_in[15];
    float* out = (float*)d_out;

    char* wsb = (char*)d_ws;
    size_t off = 0;
    auto carve32 = [&](size_t elems) { u32* p = (u32*)(wsb + off); off += elems * 4; return p; };
    u32* BigT_i  = carve32((size_t)2560 * 512);
    u32* WxT_i   = carve32((size_t)512 * 512);
    u32* WrT_i   = carve32((size_t)512 * 512);
    u32* mem_i   = carve32((size_t)1024 * 512);
    u32* memT_i  = carve32((size_t)512 * 1024);
    u32* wwT_i   = carve32((size_t)1024 * 256);
    u32* wr_i    = carve32((size_t)256 * 1024);
    u32* h_i     = carve32((size_t)256 * 512);
    u32* r_i     = carve32((size_t)256 * 512);
    u32* eT_i    = carve32((size_t)512 * 256);
    u32* aT_i    = carve32((size_t)512 * 256);
    u32* kh_i    = carve32((size_t)512 * 512);
    auto carveF = [&](size_t elems) { float* p = (float*)(wsb + off); off += elems * sizeof(float); return p; };
    float* memf   = carveF((size_t)N_ * M_);
    float* wwf    = carveF((size_t)B_ * N_);
    float* wrf    = carveF((size_t)B_ * N_);
    float* logits = carveF((size_t)2 * B_ * N_);
    float* ssqp   = carveF((size_t)N_ * 8);
    float* w6w    = carveF(H_ * 6);
    float* w6r    = carveF(H_ * 6);
    // barrier region: NB_ slots (64B apart) + flag on its own line
    off = (off + 127) & ~(size_t)127;
    unsigned* slots = (unsigned*)(wsb + off);           // slots[NB_*16]
    unsigned* flag  = slots + NB_ * 16;                 // 64B-aligned
    off += (NB_ * 16 + 16) * sizeof(unsigned) + 64;

    // ---- prologue: weight decomposition + state init (also zeroes the barrier region) ----
    decomp_t<<<dim3(16, 16), 256, 0, stream>>>(Whw, M_ + 6, 0, 512, BigT_i);                        // rows 0-511
    decomp_t<<<dim3(16, 16), 256, 0, stream>>>(Whr, M_ + 6, 0, 512, BigT_i + (size_t)512 * 512);    // rows 512-1023
    decomp_t<<<dim3(16, 16), 256, 0, stream>>>(Wo, 512, 0, 512, BigT_i + (size_t)1024 * 512);       // rows 1024-1535
    decomp_t<<<dim3(16, 32), 256, 0, stream>>>(Wea, 1024, 0, 512, BigT_i + (size_t)1536 * 512);     // rows 1536-2559
    decomp_t<<<dim3(16, 16), 256, 0, stream>>>(Wx, 512, 0, 512, WxT_i);
    decomp_t<<<dim3(16, 16), 256, 0, stream>>>(Wr, 512, 0, 512, WrT_i);
    wh6_kernel<<<2, 512, 0, stream>>>(Whw, Whr, w6w, w6r, slots);
    init_mem<<<N_, 256, 0, stream>>>(mem0, memf, mem_i, memT_i);
    init_w<<<B_, 256, 0, stream>>>(wr0, ww0, wrf, wwf, wr_i, wwT_i);
    init_h<<<B_, 64, 0, stream>>>(h0, h_i);
    // xwx for all (t,b) -> stored in d_out slots [b][t][:]
    gemm2_xwx<<<dim3(8, 512), 256, 0, stream>>>(x, WxT_i, out);
    // ea for step 0 from h0
    gemm32_pro<<<dim3(16, 8), 256, 0, stream>>>(h_i, 512, BigT_i + (size_t)1536 * 512, 512, 512,
                                                EpiEA0{bea, eT_i, aT_i});

    // ---- the entire T-loop: one persistent kernel, fence-free, interleaved planes ----
    NtmArgs A;
    A.BigT = BigT_i; A.WrT = WrT_i;
    A.mem_i = mem_i; A.memT_i = memT_i; A.wwT_i = wwT_i; A.wr_i = wr_i;
    A.h_i = h_i; A.r_i = r_i; A.eT_i = eT_i; A.aT_i = aT_i; A.kh_i = kh_i;
    A.memf = memf; A.wwf = wwf; A.wrf = wrf; A.logits = logits; A.ssqp = ssqp;
    A.w6w = w6w; A.w6r = w6r; A.bh = bh; A.bhw = bhw; A.bhr = bhr; A.bea = bea; A.bo = bo;
    A.out = out;
    A.slots = slots;
    A.flag = flag;
    ntm_loop<<<dim3(NB_), dim3(256), 0, stream>>>(A);
}